// Round 1
// baseline (693.681 us; speedup 1.0000x reference)
//
#include <hip/hip_runtime.h>

typedef _Float16 f16;
typedef _Float16 f16x8 __attribute__((ext_vector_type(8)));
typedef _Float16 f16x4 __attribute__((ext_vector_type(4)));
typedef float f32x4 __attribute__((ext_vector_type(4)));

__device__ __forceinline__ void gload16(const void* g, void* l) {
  __builtin_amdgcn_global_load_lds(
      (const __attribute__((address_space(1))) void*)g,
      (__attribute__((address_space(3))) void*)l, 16, 0, 0);
}

// ---------------- GEMM: C = alpha * A(M,K) * B(N,K)^T  [+ bias], optional transposed C write
// 128x128 tile, BK=32, 256 threads (4 waves, each 64x64 = 4x4 frags of 16x16x32 f16 MFMA)
template<typename OutT, bool BIAS, bool TRANSC>
__global__ __launch_bounds__(256)
void gemm_bt(const f16* __restrict__ A, const f16* __restrict__ B,
             OutT* __restrict__ C, const float* __restrict__ bias,
             int K, int lda, int ldb, int ldc,
             long sA, long sB, long sC, float alpha)
{
  __shared__ f16 lA[128*32];
  __shared__ f16 lB[128*32];
  const int bz = blockIdx.z;
  A += bz * sA; B += bz * sB; C += bz * sC;
  const int brow = blockIdx.y << 7;
  const int bcol = blockIdx.x << 7;
  const int tid = threadIdx.x;
  const int lane = tid & 63;
  const int wid = tid >> 6;
  const int wr = (wid >> 1) << 6;
  const int wc = (wid & 1) << 6;
  const int fr = lane & 15;
  const int kq = lane >> 4;

  const int r = tid >> 2, kb = tid & 3;
  const f16* gA0 = A + (long)(brow + r) * lda + kb * 8;
  const f16* gA1 = A + (long)(brow + 64 + r) * lda + kb * 8;
  const f16* gB0 = B + (long)(bcol + r) * ldb + kb * 8;
  const f16* gB1 = B + (long)(bcol + 64 + r) * ldb + kb * 8;
  f16* lAd0 = &lA[tid * 8];
  f16* lAd1 = &lA[2048 + tid * 8];
  f16* lBd0 = &lB[tid * 8];
  f16* lBd1 = &lB[2048 + tid * 8];

  f32x4 acc[4][4] = {};

  for (int t = 0; t < K; t += 32) {
    gload16(gA0 + t, lAd0);
    gload16(gA1 + t, lAd1);
    gload16(gB0 + t, lBd0);
    gload16(gB1 + t, lBd1);
    __syncthreads();   // compiler emits vmcnt(0) drain before s_barrier
    f16x8 av[4], bv[4];
#pragma unroll
    for (int m = 0; m < 4; m++)
      av[m] = *(const f16x8*)&lA[(wr + m * 16 + fr) * 32 + kq * 8];
#pragma unroll
    for (int n = 0; n < 4; n++)
      bv[n] = *(const f16x8*)&lB[(wc + n * 16 + fr) * 32 + kq * 8];
#pragma unroll
    for (int m = 0; m < 4; m++)
#pragma unroll
      for (int n = 0; n < 4; n++)
        acc[m][n] = __builtin_amdgcn_mfma_f32_16x16x32_f16(av[m], bv[n], acc[m][n], 0, 0, 0);
    __syncthreads();
  }

#pragma unroll
  for (int m = 0; m < 4; m++)
#pragma unroll
    for (int n = 0; n < 4; n++) {
      const int row0 = brow + wr + m * 16 + kq * 4;
      const int col  = bcol + wc + n * 16 + fr;
      if constexpr (TRANSC) {
        f16x4 v;
#pragma unroll
        for (int i = 0; i < 4; i++) v[i] = (f16)(acc[m][n][i] * alpha);
        *(f16x4*)&C[(long)col * ldc + row0] = v;   // C^T write: 4 contiguous rows
      } else {
        float bb = 0.f;
        if constexpr (BIAS) bb = bias[col];
#pragma unroll
        for (int i = 0; i < 4; i++)
          C[(long)(row0 + i) * ldc + col] = (OutT)(acc[m][n][i] * alpha + bb);
      }
    }
}

// ---------------- f32 -> f16 convert (vectorized x4)
__global__ __launch_bounds__(256)
void cvt_f32_f16(const float* __restrict__ in, f16* __restrict__ out, long n4) {
  long i = (long)blockIdx.x * 256 + threadIdx.x;
  if (i >= n4) return;
  float4 v = ((const float4*)in)[i];
  f16x4 o = {(f16)v.x, (f16)v.y, (f16)v.z, (f16)v.w};
  ((f16x4*)out)[i] = o;
}

// ---------------- f16 32x32-tile transpose (per-batch strides)
__global__ __launch_bounds__(256)
void transpose_f16(const f16* __restrict__ in, f16* __restrict__ out,
                   int ldi, int ldo, long sI, long sO) {
  __shared__ f16 t[32][33];
  const int b = blockIdx.z;
  const f16* src = in + (long)b * sI;
  f16* dst = out + (long)b * sO;
  const int r0 = blockIdx.x * 32, c0 = blockIdx.y * 32;
  const int tx = threadIdx.x, ty = threadIdx.y;  // (32,8)
#pragma unroll
  for (int j = 0; j < 32; j += 8)
    t[ty + j][tx] = src[(long)(r0 + ty + j) * ldi + c0 + tx];
  __syncthreads();
#pragma unroll
  for (int j = 0; j < 32; j += 8)
    dst[(long)(c0 + ty + j) * ldo + r0 + tx] = t[tx][ty + j];
}

// ---------------- 2x2 tile norms^2 for q (tau=0) and k (tau=1) slices of qkv
// qkv: (4,2048,3072) f16. norms: (4,1024,512) f32.
__global__ __launch_bounds__(256)
void tile_norms(const f16* __restrict__ qkv, float* __restrict__ nq, float* __restrict__ nk) {
  long i = (long)blockIdx.x * 256 + threadIdx.x;  // 4*1024*128 per tensor
  const int tau = blockIdx.y;
  const int d8 = (int)(i & 127);
  const int s2 = (int)((i >> 7) & 1023);
  const int b  = (int)(i >> 17);
  const f16* p0 = qkv + ((long)b * 2048 + 2 * s2) * 3072 + tau * 1024 + d8 * 8;
  f16x8 r0 = *(const f16x8*)p0;
  f16x8 r1 = *(const f16x8*)(p0 + 3072);
  float oo[4];
#pragma unroll
  for (int j = 0; j < 4; j++) {
    float a = (float)r0[2*j], c = (float)r0[2*j+1];
    float d = (float)r1[2*j], e = (float)r1[2*j+1];
    oo[j] = a*a + c*c + d*d + e*e;
  }
  float* dst = (tau ? nk : nq) + ((long)b * 1024 + s2) * 512 + d8 * 4;
  float4 o = {oo[0], oo[1], oo[2], oo[3]};
  *(float4*)dst = o;
}

// ---------------- WO row norms^2 (exact f32): one wave per row of (8192,1024)
__global__ __launch_bounds__(256)
void row_norms(const float* __restrict__ WO, float* __restrict__ wno) {
  const int wid = threadIdx.x >> 6, lane = threadIdx.x & 63;
  const long row = (long)blockIdx.x * 4 + wid;
  const float* p = WO + row * 1024;
  float s = 0.f;
#pragma unroll
  for (int j = 0; j < 4; j++) {
    float4 v = *(const float4*)(p + lane * 4 + j * 256);
    s += v.x*v.x + v.y*v.y + v.z*v.z + v.w*v.w;
  }
  for (int off = 32; off; off >>= 1) s += __shfl_down(s, off, 64);
  if (lane == 0) wno[row] = s;
}

// ---------------- exact radix-select of rank-r value (upper-middle order stat)
// 12 problems: 0-3 q norms (N=524288,r=262144), 4-7 k norms, 8-11 WO rows (N=2048,r=1024)
__global__ __launch_bounds__(256)
void select_init(unsigned* hist, unsigned* prefix, unsigned* rankrem) {
  int i = blockIdx.x * 256 + threadIdx.x;
  if (i < 12 * 2048) hist[i] = 0;
  if (i < 12) { prefix[i] = 0; rankrem[i] = (i < 8) ? 262144u : 1024u; }
}

__global__ __launch_bounds__(256)
void hist_pass(const float* __restrict__ nq, const float* __restrict__ nk,
               const float* __restrict__ wno, unsigned* __restrict__ hist,
               const unsigned* __restrict__ prefix,
               int shift, int nbins, unsigned himask) {
  __shared__ unsigned lh[2048];
  const int pid = blockIdx.y;
  for (int i = threadIdx.x; i < nbins; i += 256) lh[i] = 0;
  __syncthreads();
  const float* base; long N;
  if (pid < 4)      { base = nq  + (long)pid       * 524288; N = 524288; }
  else if (pid < 8) { base = nk  + (long)(pid - 4) * 524288; N = 524288; }
  else              { base = wno + (long)(pid - 8) * 2048;   N = 2048;  }
  const unsigned pref = prefix[pid];
  long chunk = (N + gridDim.x - 1) / gridDim.x;
  long s = (long)blockIdx.x * chunk;
  long e = s + chunk; if (e > N) e = N;
  for (long i = s + threadIdx.x; i < e; i += 256) {
    unsigned u = __float_as_uint(base[i]);
    if ((u & himask) == pref) atomicAdd(&lh[(u >> shift) & (nbins - 1)], 1u);
  }
  __syncthreads();
  for (int i = threadIdx.x; i < nbins; i += 256)
    if (lh[i]) atomicAdd(&hist[pid * 2048 + i], lh[i]);
}

__global__ __launch_bounds__(256)
void scan_pass(unsigned* __restrict__ hist, unsigned* __restrict__ prefix,
               unsigned* __restrict__ rankrem, float* __restrict__ thr,
               int shift, int nbins, int final_pass) {
  __shared__ unsigned lh[2048];
  const int pid = blockIdx.x;
  unsigned* h = hist + pid * 2048;
  for (int i = threadIdx.x; i < nbins; i += 256) { lh[i] = h[i]; h[i] = 0; }
  __syncthreads();
  if (threadIdx.x == 0) {
    unsigned r = rankrem[pid], accu = 0; int sel = 0;
    for (int i = 0; i < nbins; i++) {
      unsigned c = lh[i];
      if (accu + c > r) { sel = i; break; }
      accu += c;
    }
    rankrem[pid] = r - accu;
    unsigned np = prefix[pid] | ((unsigned)sel << shift);
    prefix[pid] = np;
    if (final_pass) thr[pid] = __uint_as_float(np);
  }
}

// ---------------- apply 2x2-tile mask in place on q/k slices of qkv
__global__ __launch_bounds__(256)
void apply_mask_qk(f16* __restrict__ qkv, const float* __restrict__ nq,
                   const float* __restrict__ nk, const float* __restrict__ thr) {
  long i = (long)blockIdx.x * 256 + threadIdx.x;  // 2^20 per tensor
  const int tau = blockIdx.y;
  const int d8 = (int)(i & 127);
  const int s  = (int)((i >> 7) & 2047);
  const int b  = (int)(i >> 18);
  const float* nrm = (tau ? nk : nq) + ((long)b * 1024 + (s >> 1)) * 512 + d8 * 4;
  const float t = thr[tau * 4 + b];
  f16* p = qkv + ((long)b * 2048 + s) * 3072 + tau * 1024 + d8 * 8;
  f16x8 v = *(f16x8*)p;
  float4 nv = *(const float4*)nrm;
  if (nv.x < t) { v[0] = (f16)0.f; v[1] = (f16)0.f; }
  if (nv.y < t) { v[2] = (f16)0.f; v[3] = (f16)0.f; }
  if (nv.z < t) { v[4] = (f16)0.f; v[5] = (f16)0.f; }
  if (nv.w < t) { v[6] = (f16)0.f; v[7] = (f16)0.f; }
  *(f16x8*)p = v;
}

// ---------------- WO row mask + f16 convert
__global__ __launch_bounds__(256)
void wo_mask(const float* __restrict__ WO, const float* __restrict__ wno,
             const float* __restrict__ thr, f16* __restrict__ woh) {
  long i = (long)blockIdx.x * 256 + threadIdx.x;  // 8192*256
  const int d4 = (int)(i & 255);
  const long row = i >> 8;
  const int b = (int)(row >> 11);
  const float m = (wno[row] >= thr[8 + b]) ? 1.f : 0.f;
  float4 v = *(const float4*)(WO + row * 1024 + d4 * 4);
  f16x4 o = {(f16)(v.x * m), (f16)(v.y * m), (f16)(v.z * m), (f16)(v.w * m)};
  *(f16x4*)(woh + row * 1024 + d4 * 4) = o;
}

extern "C" void kernel_launch(void* const* d_in, const int* in_sizes, int n_in,
                              void* d_out, int out_size, void* d_ws, size_t ws_size,
                              hipStream_t stream) {
  const float* x    = (const float*)d_in[0];   // (4,2048,1024)
  const float* Wqkv = (const float*)d_in[1];   // (3072,1024)
  const float* bqkv = (const float*)d_in[2];   // (3072,) zeros
  const float* WO   = (const float*)d_in[3];   // (4,1,2048,1024)
  float* out = (float*)d_out;                  // (4,2048,1024) f32

  char* w = (char*)d_ws;
  auto alloc = [&](size_t bytes) { char* p = w; w += (bytes + 255) & ~(size_t)255; return p; };
  f16*      xh      = (f16*)alloc(8192L * 1024 * 2);
  f16*      wh      = (f16*)alloc(3072L * 1024 * 2);
  f16*      xT      = (f16*)alloc(4L * 1024 * 2048 * 2);
  f16*      qkv     = (f16*)alloc(8192L * 3072 * 2);
  float*    nq      = (float*)alloc(4L * 524288 * 4);
  float*    nk      = (float*)alloc(4L * 524288 * 4);
  float*    wno     = (float*)alloc(8192L * 4);
  unsigned* hist    = (unsigned*)alloc(12L * 2048 * 4);
  unsigned* prefix  = (unsigned*)alloc(256);
  unsigned* rankrem = (unsigned*)alloc(256);
  float*    thr     = (float*)alloc(256);
  f16*      woh     = (f16*)alloc(8192L * 1024 * 2);
  f16*      WOT     = (f16*)alloc(4L * 1024 * 2048 * 2);
  f16*      PqT     = (f16*)alloc(4L * 1024 * 2048 * 2);
  f16*      Zt      = (f16*)alloc(4L * 1024 * 1024 * 2);
  f16*      t1T     = (f16*)alloc(4L * 1024 * 2048 * 2);
  f16*      YT      = (f16*)alloc(4L * 1024 * 1024 * 2);
  f16*      T3T     = (f16*)alloc(4L * 1024 * 1024 * 2);
  f16*      t2T     = (f16*)nq;  // overlay: nq+nk (16.8MB) dead before G_D writes t2T
  if ((size_t)(w - (char*)d_ws) > ws_size) return;  // workspace too small: fail visibly

  // 1. fp16 conversions
  cvt_f32_f16<<<8192, 256, 0, stream>>>(x, xh, 8192L * 1024 / 4);
  cvt_f32_f16<<<3072, 256, 0, stream>>>(Wqkv, wh, 3072L * 1024 / 4);
  // 2. qkv = x @ Wqkv^T + bqkv   (M=8192,N=3072,K=1024)
  gemm_bt<f16, true, false><<<dim3(24, 64, 1), 256, 0, stream>>>(
      xh, wh, qkv, bqkv, 1024, 1024, 1024, 3072, 0, 0, 0, 1.f);
  // 3. xT (per batch 1024x2048)
  transpose_f16<<<dim3(64, 32, 4), dim3(32, 8), 0, stream>>>(
      xh, xT, 1024, 2048, 2048L * 1024, 1024L * 2048);
  // 4. norms
  tile_norms<<<dim3(2048, 2), 256, 0, stream>>>(qkv, nq, nk);
  row_norms<<<2048, 256, 0, stream>>>(WO, wno);
  // 5. exact medians via 3-pass radix select (bits 31:21 / 20:10 / 9:0)
  select_init<<<96, 256, 0, stream>>>(hist, prefix, rankrem);
  hist_pass<<<dim3(32, 12), 256, 0, stream>>>(nq, nk, wno, hist, prefix, 21, 2048, 0u);
  scan_pass<<<12, 256, 0, stream>>>(hist, prefix, rankrem, thr, 21, 2048, 0);
  hist_pass<<<dim3(32, 12), 256, 0, stream>>>(nq, nk, wno, hist, prefix, 10, 2048, 0xFFE00000u);
  scan_pass<<<12, 256, 0, stream>>>(hist, prefix, rankrem, thr, 10, 2048, 0);
  hist_pass<<<dim3(32, 12), 256, 0, stream>>>(nq, nk, wno, hist, prefix, 0, 1024, 0xFFFFFC00u);
  scan_pass<<<12, 256, 0, stream>>>(hist, prefix, rankrem, thr, 0, 1024, 1);
  // 6. masks
  apply_mask_qk<<<dim3(4096, 2), 256, 0, stream>>>(qkv, nq, nk, thr);
  wo_mask<<<8192, 256, 0, stream>>>(WO, wno, thr, woh);
  // 7. transposes of masked operands
  transpose_f16<<<dim3(64, 32, 4), dim3(32, 8), 0, stream>>>(
      qkv, PqT, 3072, 2048, 2048L * 3072, 1024L * 2048);             // Pq^T
  transpose_f16<<<dim3(64, 32, 4), dim3(32, 8), 0, stream>>>(
      woh, WOT, 1024, 2048, 2048L * 1024, 1024L * 2048);             // WO_^T
  // 8. reassociated chain: out = x·Pq^T·Pk·x^T·v·WO_^T·x / 32
  // G_A: Zt[e,d] = sum_l xT[e,l]·WOT[d,l]           (M=1024,N=1024,K=2048)
  gemm_bt<f16, false, false><<<dim3(8, 8, 4), 256, 0, stream>>>(
      xT, WOT, Zt, nullptr, 2048, 2048, 2048, 1024,
      1024L * 2048, 1024L * 2048, 1024L * 1024, 1.f);
  // G_B: t1 = v·Zt, written transposed -> t1T[e,s]   (M=2048,N=1024,K=1024)
  gemm_bt<f16, false, true><<<dim3(8, 16, 4), 256, 0, stream>>>(
      qkv + 2048, Zt, t1T, nullptr, 1024, 3072, 1024, 2048,
      2048L * 3072, 1024L * 1024, 1024L * 2048, 1.f);
  // G_C: YT[e,d] = (1/32)·sum_s t1T[e,s]·xT[d,s]    (M=1024,N=1024,K=2048)
  gemm_bt<f16, false, false><<<dim3(8, 8, 4), 256, 0, stream>>>(
      t1T, xT, YT, nullptr, 2048, 2048, 2048, 1024,
      1024L * 2048, 1024L * 2048, 1024L * 1024, 0.03125f);
  // G_D: t2 = Pk·Y ·(1/16), written transposed -> t2T[e,s]  (M=2048,N=1024,K=1024)
  gemm_bt<f16, false, true><<<dim3(8, 16, 4), 256, 0, stream>>>(
      qkv + 1024, YT, t2T, nullptr, 1024, 3072, 1024, 2048,
      2048L * 3072, 1024L * 1024, 1024L * 2048, 0.0625f);
  // G_E: T3T[e,d] = (1/32)·sum_s t2T[e,s]·PqT[d,s]  (M=1024,N=1024,K=2048)
  gemm_bt<f16, false, false><<<dim3(8, 8, 4), 256, 0, stream>>>(
      t2T, PqT, T3T, nullptr, 2048, 2048, 2048, 1024,
      1024L * 2048, 1024L * 2048, 1024L * 1024, 0.03125f);
  // G_F: out[s,e] = 512·sum_d xh[s,d]·T3T[e,d]  (total scale 512/(32·16·32)=1/32)
  gemm_bt<float, false, false><<<dim3(8, 16, 4), 256, 0, stream>>>(
      xh, T3T, out, nullptr, 1024, 1024, 1024, 1024,
      2048L * 1024, 1024L * 1024, 2048L * 1024, 512.f);
}

// Round 2
// 481.123 us; speedup vs baseline: 1.4418x; 1.4418x over previous
//
#include <hip/hip_runtime.h>

typedef _Float16 f16;
typedef _Float16 f16x8 __attribute__((ext_vector_type(8)));
typedef _Float16 f16x4 __attribute__((ext_vector_type(4)));
typedef float f32x4 __attribute__((ext_vector_type(4)));

__device__ __forceinline__ void gload16(const void* g, void* l) {
  __builtin_amdgcn_global_load_lds(
      (const __attribute__((address_space(1))) void*)g,
      (__attribute__((address_space(3))) void*)l, 16, 0, 0);
}

// ---------------- GEMM: C = alpha * A(M,K) * B(N,K)^T  [+ bias], optional transposed C write
// 128x128 tile, BK=32, 256 threads (4 waves, each 64x64 = 4x4 frags of 16x16x32 f16 MFMA)
template<typename OutT, bool BIAS, bool TRANSC>
__global__ __launch_bounds__(256)
void gemm_bt(const f16* __restrict__ A, const f16* __restrict__ B,
             OutT* __restrict__ C, const float* __restrict__ bias,
             int K, int lda, int ldb, int ldc,
             long sA, long sB, long sC, float alpha)
{
  __shared__ f16 lA[128*32];
  __shared__ f16 lB[128*32];
  const int bz = blockIdx.z;
  A += bz * sA; B += bz * sB; C += bz * sC;
  const int brow = blockIdx.y << 7;
  const int bcol = blockIdx.x << 7;
  const int tid = threadIdx.x;
  const int lane = tid & 63;
  const int wid = tid >> 6;
  const int wr = (wid >> 1) << 6;
  const int wc = (wid & 1) << 6;
  const int fr = lane & 15;
  const int kq = lane >> 4;

  const int r = tid >> 2, kb = tid & 3;
  const f16* gA0 = A + (long)(brow + r) * lda + kb * 8;
  const f16* gA1 = A + (long)(brow + 64 + r) * lda + kb * 8;
  const f16* gB0 = B + (long)(bcol + r) * ldb + kb * 8;
  const f16* gB1 = B + (long)(bcol + 64 + r) * ldb + kb * 8;
  f16* lAd0 = &lA[tid * 8];
  f16* lAd1 = &lA[2048 + tid * 8];
  f16* lBd0 = &lB[tid * 8];
  f16* lBd1 = &lB[2048 + tid * 8];

  f32x4 acc[4][4] = {};

  for (int t = 0; t < K; t += 32) {
    gload16(gA0 + t, lAd0);
    gload16(gA1 + t, lAd1);
    gload16(gB0 + t, lBd0);
    gload16(gB1 + t, lBd1);
    __syncthreads();   // compiler emits vmcnt(0) drain before s_barrier
    f16x8 av[4], bv[4];
#pragma unroll
    for (int m = 0; m < 4; m++)
      av[m] = *(const f16x8*)&lA[(wr + m * 16 + fr) * 32 + kq * 8];
#pragma unroll
    for (int n = 0; n < 4; n++)
      bv[n] = *(const f16x8*)&lB[(wc + n * 16 + fr) * 32 + kq * 8];
#pragma unroll
    for (int m = 0; m < 4; m++)
#pragma unroll
      for (int n = 0; n < 4; n++)
        acc[m][n] = __builtin_amdgcn_mfma_f32_16x16x32_f16(av[m], bv[n], acc[m][n], 0, 0, 0);
    __syncthreads();
  }

#pragma unroll
  for (int m = 0; m < 4; m++)
#pragma unroll
    for (int n = 0; n < 4; n++) {
      const int row0 = brow + wr + m * 16 + kq * 4;
      const int col  = bcol + wc + n * 16 + fr;
      if constexpr (TRANSC) {
        f16x4 v;
#pragma unroll
        for (int i = 0; i < 4; i++) v[i] = (f16)(acc[m][n][i] * alpha);
        *(f16x4*)&C[(long)col * ldc + row0] = v;   // C^T write: 4 contiguous rows
      } else {
        float bb = 0.f;
        if constexpr (BIAS) bb = bias[col];
#pragma unroll
        for (int i = 0; i < 4; i++)
          C[(long)(row0 + i) * ldc + col] = (OutT)(acc[m][n][i] * alpha + bb);
      }
    }
}

// ---------------- f32 -> f16 convert (vectorized x4)
__global__ __launch_bounds__(256)
void cvt_f32_f16(const float* __restrict__ in, f16* __restrict__ out, long n4) {
  long i = (long)blockIdx.x * 256 + threadIdx.x;
  if (i >= n4) return;
  float4 v = ((const float4*)in)[i];
  f16x4 o = {(f16)v.x, (f16)v.y, (f16)v.z, (f16)v.w};
  ((f16x4*)out)[i] = o;
}

// ---------------- f16 32x32-tile transpose (per-batch strides)
__global__ __launch_bounds__(256)
void transpose_f16(const f16* __restrict__ in, f16* __restrict__ out,
                   int ldi, int ldo, long sI, long sO) {
  __shared__ f16 t[32][33];
  const int b = blockIdx.z;
  const f16* src = in + (long)b * sI;
  f16* dst = out + (long)b * sO;
  const int r0 = blockIdx.x * 32, c0 = blockIdx.y * 32;
  const int tx = threadIdx.x, ty = threadIdx.y;  // (32,8)
#pragma unroll
  for (int j = 0; j < 32; j += 8)
    t[ty + j][tx] = src[(long)(r0 + ty + j) * ldi + c0 + tx];
  __syncthreads();
#pragma unroll
  for (int j = 0; j < 32; j += 8)
    dst[(long)(c0 + ty + j) * ldo + r0 + tx] = t[tx][ty + j];
}

// ---------------- 2x2 tile norms^2 for q (tau=0) and k (tau=1) slices of qkv
// qkv: (4,2048,3072) f16. norms: (4,1024,512) f32.
__global__ __launch_bounds__(256)
void tile_norms(const f16* __restrict__ qkv, float* __restrict__ nq, float* __restrict__ nk) {
  long i = (long)blockIdx.x * 256 + threadIdx.x;  // 4*1024*128 per tensor
  const int tau = blockIdx.y;
  const int d8 = (int)(i & 127);
  const int s2 = (int)((i >> 7) & 1023);
  const int b  = (int)(i >> 17);
  const f16* p0 = qkv + ((long)b * 2048 + 2 * s2) * 3072 + tau * 1024 + d8 * 8;
  f16x8 r0 = *(const f16x8*)p0;
  f16x8 r1 = *(const f16x8*)(p0 + 3072);
  float oo[4];
#pragma unroll
  for (int j = 0; j < 4; j++) {
    float a = (float)r0[2*j], c = (float)r0[2*j+1];
    float d = (float)r1[2*j], e = (float)r1[2*j+1];
    oo[j] = a*a + c*c + d*d + e*e;
  }
  float* dst = (tau ? nk : nq) + ((long)b * 1024 + s2) * 512 + d8 * 4;
  float4 o = {oo[0], oo[1], oo[2], oo[3]};
  *(float4*)dst = o;
}

// ---------------- WO row norms^2 (exact f32): one wave per row of (8192,1024)
__global__ __launch_bounds__(256)
void row_norms(const float* __restrict__ WO, float* __restrict__ wno) {
  const int wid = threadIdx.x >> 6, lane = threadIdx.x & 63;
  const long row = (long)blockIdx.x * 4 + wid;
  const float* p = WO + row * 1024;
  float s = 0.f;
#pragma unroll
  for (int j = 0; j < 4; j++) {
    float4 v = *(const float4*)(p + lane * 4 + j * 256);
    s += v.x*v.x + v.y*v.y + v.z*v.z + v.w*v.w;
  }
  for (int off = 32; off; off >>= 1) s += __shfl_down(s, off, 64);
  if (lane == 0) wno[row] = s;
}

// ---------------- exact radix-select of rank-r value (upper-middle order stat)
// 12 problems: 0-3 q norms (N=524288,r=262144), 4-7 k norms, 8-11 WO rows (N=2048,r=1024)
__global__ __launch_bounds__(256)
void select_init(unsigned* hist, unsigned* prefix, unsigned* rankrem) {
  int i = blockIdx.x * 256 + threadIdx.x;
  if (i < 12 * 2048) hist[i] = 0;
  if (i < 12) { prefix[i] = 0; rankrem[i] = (i < 8) ? 262144u : 1024u; }
}

__global__ __launch_bounds__(256)
void hist_pass(const float* __restrict__ nq, const float* __restrict__ nk,
               const float* __restrict__ wno, unsigned* __restrict__ hist,
               const unsigned* __restrict__ prefix,
               int shift, int nbins, unsigned himask) {
  __shared__ unsigned lh[2048];
  const int pid = blockIdx.y;
  for (int i = threadIdx.x; i < nbins; i += 256) lh[i] = 0;
  __syncthreads();
  const float* base; long N;
  if (pid < 4)      { base = nq  + (long)pid       * 524288; N = 524288; }
  else if (pid < 8) { base = nk  + (long)(pid - 4) * 524288; N = 524288; }
  else              { base = wno + (long)(pid - 8) * 2048;   N = 2048;  }
  const unsigned pref = prefix[pid];
  long chunk = (N + gridDim.x - 1) / gridDim.x;
  long s = (long)blockIdx.x * chunk;
  long e = s + chunk; if (e > N) e = N;
  for (long i = s + threadIdx.x; i < e; i += 256) {
    unsigned u = __float_as_uint(base[i]);
    if ((u & himask) == pref) atomicAdd(&lh[(u >> shift) & (nbins - 1)], 1u);
  }
  __syncthreads();
  for (int i = threadIdx.x; i < nbins; i += 256)
    if (lh[i]) atomicAdd(&hist[pid * 2048 + i], lh[i]);
}

// Parallel scan: 256 threads each own nbins/256 bins; chunk sums -> Hillis-Steele
// inclusive scan (8 LDS steps); unique owner thread resolves the bin containing
// rank r. Replaces 130us serial-LDS-latency loop (was 56% of total runtime).
__global__ __launch_bounds__(256)
void scan_pass(unsigned* __restrict__ hist, unsigned* __restrict__ prefix,
               unsigned* __restrict__ rankrem, float* __restrict__ thr,
               int shift, int nbins, int final_pass) {
  __shared__ unsigned buf[2][256];
  const int pid = blockIdx.x;
  const int tid = threadIdx.x;
  unsigned* h = hist + pid * 2048;
  const int per = nbins >> 8;  // 8 or 4
  const unsigned r = rankrem[pid];        // read BEFORE any thread can write it
  const unsigned oldpref = prefix[pid];
  unsigned local[8];
  unsigned s = 0;
#pragma unroll
  for (int j = 0; j < 8; j++) {
    if (j < per) {
      local[j] = h[tid * per + j];
      h[tid * per + j] = 0;               // re-zero for next pass
      s += local[j];
    }
  }
  buf[0][tid] = s;
  __syncthreads();
  int src = 0;
#pragma unroll
  for (int d = 1; d < 256; d <<= 1) {
    unsigned v = buf[src][tid];
    if (tid >= d) v += buf[src][tid - d];
    buf[src ^ 1][tid] = v;
    __syncthreads();
    src ^= 1;
  }
  const unsigned incl = buf[src][tid];
  const unsigned excl = incl - s;
  if (excl <= r && r < incl) {            // exactly one thread
    unsigned accu = excl;
#pragma unroll
    for (int j = 0; j < 8; j++) {
      if (j < per) {
        if (accu + local[j] > r) {
          rankrem[pid] = r - accu;
          unsigned np = oldpref | ((unsigned)(tid * per + j) << shift);
          prefix[pid] = np;
          if (final_pass) thr[pid] = __uint_as_float(np);
          break;
        }
        accu += local[j];
      }
    }
  }
}

// ---------------- apply 2x2-tile mask in place on q/k slices of qkv
__global__ __launch_bounds__(256)
void apply_mask_qk(f16* __restrict__ qkv, const float* __restrict__ nq,
                   const float* __restrict__ nk, const float* __restrict__ thr) {
  long i = (long)blockIdx.x * 256 + threadIdx.x;  // 2^20 per tensor
  const int tau = blockIdx.y;
  const int d8 = (int)(i & 127);
  const int s  = (int)((i >> 7) & 2047);
  const int b  = (int)(i >> 18);
  const float* nrm = (tau ? nk : nq) + ((long)b * 1024 + (s >> 1)) * 512 + d8 * 4;
  const float t = thr[tau * 4 + b];
  f16* p = qkv + ((long)b * 2048 + s) * 3072 + tau * 1024 + d8 * 8;
  f16x8 v = *(f16x8*)p;
  float4 nv = *(const float4*)nrm;
  if (nv.x < t) { v[0] = (f16)0.f; v[1] = (f16)0.f; }
  if (nv.y < t) { v[2] = (f16)0.f; v[3] = (f16)0.f; }
  if (nv.z < t) { v[4] = (f16)0.f; v[5] = (f16)0.f; }
  if (nv.w < t) { v[6] = (f16)0.f; v[7] = (f16)0.f; }
  *(f16x8*)p = v;
}

// ---------------- WO row mask + f16 convert
__global__ __launch_bounds__(256)
void wo_mask(const float* __restrict__ WO, const float* __restrict__ wno,
             const float* __restrict__ thr, f16* __restrict__ woh) {
  long i = (long)blockIdx.x * 256 + threadIdx.x;  // 8192*256
  const int d4 = (int)(i & 255);
  const long row = i >> 8;
  const int b = (int)(row >> 11);
  const float m = (wno[row] >= thr[8 + b]) ? 1.f : 0.f;
  float4 v = *(const float4*)(WO + row * 1024 + d4 * 4);
  f16x4 o = {(f16)(v.x * m), (f16)(v.y * m), (f16)(v.z * m), (f16)(v.w * m)};
  *(f16x4*)(woh + row * 1024 + d4 * 4) = o;
}

extern "C" void kernel_launch(void* const* d_in, const int* in_sizes, int n_in,
                              void* d_out, int out_size, void* d_ws, size_t ws_size,
                              hipStream_t stream) {
  const float* x    = (const float*)d_in[0];   // (4,2048,1024)
  const float* Wqkv = (const float*)d_in[1];   // (3072,1024)
  const float* bqkv = (const float*)d_in[2];   // (3072,) zeros
  const float* WO   = (const float*)d_in[3];   // (4,1,2048,1024)
  float* out = (float*)d_out;                  // (4,2048,1024) f32

  char* w = (char*)d_ws;
  auto alloc = [&](size_t bytes) { char* p = w; w += (bytes + 255) & ~(size_t)255; return p; };
  f16*      xh      = (f16*)alloc(8192L * 1024 * 2);
  f16*      wh      = (f16*)alloc(3072L * 1024 * 2);
  f16*      xT      = (f16*)alloc(4L * 1024 * 2048 * 2);
  f16*      qkv     = (f16*)alloc(8192L * 3072 * 2);
  float*    nq      = (float*)alloc(4L * 524288 * 4);
  float*    nk      = (float*)alloc(4L * 524288 * 4);
  float*    wno     = (float*)alloc(8192L * 4);
  unsigned* hist    = (unsigned*)alloc(12L * 2048 * 4);
  unsigned* prefix  = (unsigned*)alloc(256);
  unsigned* rankrem = (unsigned*)alloc(256);
  float*    thr     = (float*)alloc(256);
  f16*      woh     = (f16*)alloc(8192L * 1024 * 2);
  f16*      WOT     = (f16*)alloc(4L * 1024 * 2048 * 2);
  f16*      PqT     = (f16*)alloc(4L * 1024 * 2048 * 2);
  f16*      Zt      = (f16*)alloc(4L * 1024 * 1024 * 2);
  f16*      t1T     = (f16*)alloc(4L * 1024 * 2048 * 2);
  f16*      YT      = (f16*)alloc(4L * 1024 * 1024 * 2);
  f16*      T3T     = (f16*)alloc(4L * 1024 * 1024 * 2);
  f16*      t2T     = (f16*)nq;  // overlay: nq+nk (16.8MB) dead before G_D writes t2T
  if ((size_t)(w - (char*)d_ws) > ws_size) return;  // workspace too small: fail visibly

  // 1. fp16 conversions
  cvt_f32_f16<<<8192, 256, 0, stream>>>(x, xh, 8192L * 1024 / 4);
  cvt_f32_f16<<<3072, 256, 0, stream>>>(Wqkv, wh, 3072L * 1024 / 4);
  // 2. qkv = x @ Wqkv^T + bqkv   (M=8192,N=3072,K=1024)
  gemm_bt<f16, true, false><<<dim3(24, 64, 1), 256, 0, stream>>>(
      xh, wh, qkv, bqkv, 1024, 1024, 1024, 3072, 0, 0, 0, 1.f);
  // 3. xT (per batch 1024x2048)
  transpose_f16<<<dim3(64, 32, 4), dim3(32, 8), 0, stream>>>(
      xh, xT, 1024, 2048, 2048L * 1024, 1024L * 2048);
  // 4. norms
  tile_norms<<<dim3(2048, 2), 256, 0, stream>>>(qkv, nq, nk);
  row_norms<<<2048, 256, 0, stream>>>(WO, wno);
  // 5. exact medians via 3-pass radix select (bits 31:21 / 20:10 / 9:0)
  select_init<<<96, 256, 0, stream>>>(hist, prefix, rankrem);
  hist_pass<<<dim3(32, 12), 256, 0, stream>>>(nq, nk, wno, hist, prefix, 21, 2048, 0u);
  scan_pass<<<12, 256, 0, stream>>>(hist, prefix, rankrem, thr, 21, 2048, 0);
  hist_pass<<<dim3(32, 12), 256, 0, stream>>>(nq, nk, wno, hist, prefix, 10, 2048, 0xFFE00000u);
  scan_pass<<<12, 256, 0, stream>>>(hist, prefix, rankrem, thr, 10, 2048, 0);
  hist_pass<<<dim3(32, 12), 256, 0, stream>>>(nq, nk, wno, hist, prefix, 0, 1024, 0xFFFFFC00u);
  scan_pass<<<12, 256, 0, stream>>>(hist, prefix, rankrem, thr, 0, 1024, 1);
  // 6. masks
  apply_mask_qk<<<dim3(4096, 2), 256, 0, stream>>>(qkv, nq, nk, thr);
  wo_mask<<<8192, 256, 0, stream>>>(WO, wno, thr, woh);
  // 7. transposes of masked operands
  transpose_f16<<<dim3(64, 32, 4), dim3(32, 8), 0, stream>>>(
      qkv, PqT, 3072, 2048, 2048L * 3072, 1024L * 2048);             // Pq^T
  transpose_f16<<<dim3(64, 32, 4), dim3(32, 8), 0, stream>>>(
      woh, WOT, 1024, 2048, 2048L * 1024, 1024L * 2048);             // WO_^T
  // 8. reassociated chain: out = x·Pq^T·Pk·x^T·v·WO_^T·x / 32
  // G_A: Zt[e,d] = sum_l xT[e,l]·WOT[d,l]           (M=1024,N=1024,K=2048)
  gemm_bt<f16, false, false><<<dim3(8, 8, 4), 256, 0, stream>>>(
      xT, WOT, Zt, nullptr, 2048, 2048, 2048, 1024,
      1024L * 2048, 1024L * 2048, 1024L * 1024, 1.f);
  // G_B: t1 = v·Zt, written transposed -> t1T[e,s]   (M=2048,N=1024,K=1024)
  gemm_bt<f16, false, true><<<dim3(8, 16, 4), 256, 0, stream>>>(
      qkv + 2048, Zt, t1T, nullptr, 1024, 3072, 1024, 2048,
      2048L * 3072, 1024L * 1024, 1024L * 2048, 1.f);
  // G_C: YT[e,d] = (1/32)·sum_s t1T[e,s]·xT[d,s]    (M=1024,N=1024,K=2048)
  gemm_bt<f16, false, false><<<dim3(8, 8, 4), 256, 0, stream>>>(
      t1T, xT, YT, nullptr, 2048, 2048, 2048, 1024,
      1024L * 2048, 1024L * 2048, 1024L * 1024, 0.03125f);
  // G_D: t2 = Pk·Y ·(1/16), written transposed -> t2T[e,s]  (M=2048,N=1024,K=1024)
  gemm_bt<f16, false, true><<<dim3(8, 16, 4), 256, 0, stream>>>(
      qkv + 1024, YT, t2T, nullptr, 1024, 3072, 1024, 2048,
      2048L * 3072, 1024L * 1024, 1024L * 2048, 0.0625f);
  // G_E: T3T[e,d] = (1/32)·sum_s t2T[e,s]·PqT[d,s]  (M=1024,N=1024,K=2048)
  gemm_bt<f16, false, false><<<dim3(8, 8, 4), 256, 0, stream>>>(
      t2T, PqT, T3T, nullptr, 2048, 2048, 2048, 1024,
      1024L * 2048, 1024L * 2048, 1024L * 1024, 0.03125f);
  // G_F: out[s,e] = 512·sum_d xh[s,d]·T3T[e,d]  (total scale 512/(32·16·32)=1/32)
  gemm_bt<float, false, false><<<dim3(8, 16, 4), 256, 0, stream>>>(
      xh, T3T, out, nullptr, 1024, 1024, 1024, 1024,
      2048L * 1024, 1024L * 1024, 2048L * 1024, 512.f);
}

// Round 3
// 391.456 us; speedup vs baseline: 1.7721x; 1.2291x over previous
//
#include <hip/hip_runtime.h>

typedef _Float16 f16;
typedef _Float16 f16x8 __attribute__((ext_vector_type(8)));
typedef _Float16 f16x4 __attribute__((ext_vector_type(4)));
typedef float f32x4 __attribute__((ext_vector_type(4)));

__device__ __forceinline__ void gload16(const void* g, void* l) {
  __builtin_amdgcn_global_load_lds(
      (const __attribute__((address_space(1))) void*)g,
      (__attribute__((address_space(3))) void*)l, 16, 0, 0);
}

// ---------------- GEMM body: C = alpha * A(M,K) * B(N,K)^T [+ bias], optional C^T write
// 128x128 tile, BK=32, 256 threads (4 waves, each 64x64 = 4x4 frags of 16x16x32 f16 MFMA).
// LDS layout is 16B-granule swizzled: logical (row, kq) lives at granule row*4 + (kq ^ ((row>>1)&3)).
// global_load_lds writes linearly (granule = tid), so the SOURCE address carries the inverse
// permutation (skq) and the ds_read applies the same XOR (kqsw). Quarter-wave b128 reads then
// cover all 8 bank-groups exactly twice (2-way = free) instead of 8-way conflicting.
template<typename OutT, bool BIAS, bool TRANSC>
__device__ __forceinline__ void gemm_body(
    const f16* __restrict__ A, const f16* __restrict__ B,
    OutT* __restrict__ C, const float* __restrict__ bias,
    int K, int lda, int ldb, int ldc, float alpha,
    f16* lA, f16* lB)
{
  const int brow = blockIdx.y << 7;
  const int bcol = blockIdx.x << 7;
  const int tid = threadIdx.x;
  const int lane = tid & 63;
  const int wid = tid >> 6;
  const int wr = (wid >> 1) << 6;
  const int wc = (wid & 1) << 6;
  const int fr = lane & 15;
  const int kq = lane >> 4;
  const int kqsw = kq ^ ((fr >> 1) & 3);      // swizzled read slot (per-thread constant)

  const int srow = tid >> 2;                   // staging: granule tid holds (srow, skq)
  const int skq  = (tid & 3) ^ ((tid >> 3) & 3);
  const f16* gA0 = A + (long)(brow + srow) * lda + skq * 8;
  const f16* gA1 = A + (long)(brow + 64 + srow) * lda + skq * 8;
  const f16* gB0 = B + (long)(bcol + srow) * ldb + skq * 8;
  const f16* gB1 = B + (long)(bcol + 64 + srow) * ldb + skq * 8;
  f16* lAd0 = &lA[tid * 8];
  f16* lAd1 = &lA[2048 + tid * 8];
  f16* lBd0 = &lB[tid * 8];
  f16* lBd1 = &lB[2048 + tid * 8];

  f32x4 acc[4][4] = {};

  for (int t = 0; t < K; t += 32) {
    gload16(gA0 + t, lAd0);
    gload16(gA1 + t, lAd1);
    gload16(gB0 + t, lBd0);
    gload16(gB1 + t, lBd1);
    __syncthreads();
    f16x8 av[4], bv[4];
#pragma unroll
    for (int m = 0; m < 4; m++)
      av[m] = *(const f16x8*)&lA[(wr + m * 16 + fr) * 32 + kqsw * 8];
#pragma unroll
    for (int n = 0; n < 4; n++)
      bv[n] = *(const f16x8*)&lB[(wc + n * 16 + fr) * 32 + kqsw * 8];
#pragma unroll
    for (int m = 0; m < 4; m++)
#pragma unroll
      for (int n = 0; n < 4; n++)
        acc[m][n] = __builtin_amdgcn_mfma_f32_16x16x32_f16(av[m], bv[n], acc[m][n], 0, 0, 0);
    __syncthreads();
  }

#pragma unroll
  for (int m = 0; m < 4; m++)
#pragma unroll
    for (int n = 0; n < 4; n++) {
      const int row0 = brow + wr + m * 16 + kq * 4;
      const int col  = bcol + wc + n * 16 + fr;
      if constexpr (TRANSC) {
        f16x4 v;
#pragma unroll
        for (int i = 0; i < 4; i++) v[i] = (f16)(acc[m][n][i] * alpha);
        *(f16x4*)&C[(long)col * ldc + row0] = v;   // C^T write: 4 contiguous rows
      } else {
        float bb = 0.f;
        if constexpr (BIAS) bb = bias[col];
#pragma unroll
        for (int i = 0; i < 4; i++)
          C[(long)(row0 + i) * ldc + col] = (OutT)(acc[m][n][i] * alpha + bb);
      }
    }
}

template<typename OutT, bool BIAS, bool TRANSC>
__global__ __launch_bounds__(256)
void gemm_bt(const f16* __restrict__ A, const f16* __restrict__ B,
             OutT* __restrict__ C, const float* __restrict__ bias,
             int K, int lda, int ldb, int ldc,
             long sA, long sB, long sC, float alpha)
{
  __shared__ f16 lA[128*32];
  __shared__ f16 lB[128*32];
  const int bz = blockIdx.z;
  gemm_body<OutT, BIAS, TRANSC>(A + bz * sA, B + bz * sB, C + bz * sC, bias,
                                K, lda, ldb, ldc, alpha, lA, lB);
}

// Merged stage-1 launch: 3 independent products x 4 batches (blockIdx.z = p*4+b).
// All are M=N=1024, K=2048, lda=ldb=2048, ldc=1024, alpha shared.
__global__ __launch_bounds__(256)
void gemm3(const f16* __restrict__ Aa, const f16* __restrict__ Ba, f16* __restrict__ Ca,
           const f16* __restrict__ Ab, const f16* __restrict__ Bb, f16* __restrict__ Cb,
           const f16* __restrict__ Ac, const f16* __restrict__ Bc, f16* __restrict__ Cc,
           float alpha)
{
  __shared__ f16 lA[128*32];
  __shared__ f16 lB[128*32];
  const int p = blockIdx.z >> 2, b = blockIdx.z & 3;
  const f16* A; const f16* B; f16* C;
  if (p == 0)      { A = Aa; B = Ba; C = Ca; }
  else if (p == 1) { A = Ab; B = Bb; C = Cb; }
  else             { A = Ac; B = Bc; C = Cc; }
  A += (long)b * (1024L * 2048);
  B += (long)b * (1024L * 2048);
  C += (long)b * (1024L * 1024);
  gemm_body<f16, false, false>(A, B, C, nullptr, 2048, 2048, 2048, 1024, alpha, lA, lB);
}

// ---------------- f32 -> f16 convert (vectorized x4)
__global__ __launch_bounds__(256)
void cvt_f32_f16(const float* __restrict__ in, f16* __restrict__ out, long n4) {
  long i = (long)blockIdx.x * 256 + threadIdx.x;
  if (i >= n4) return;
  float4 v = ((const float4*)in)[i];
  f16x4 o = {(f16)v.x, (f16)v.y, (f16)v.z, (f16)v.w};
  ((f16x4*)out)[i] = o;
}

// ---------------- f16 32x32-tile transpose (per-batch strides)
__global__ __launch_bounds__(256)
void transpose_f16(const f16* __restrict__ in, f16* __restrict__ out,
                   int ldi, int ldo, long sI, long sO) {
  __shared__ f16 t[32][33];
  const int b = blockIdx.z;
  const f16* src = in + (long)b * sI;
  f16* dst = out + (long)b * sO;
  const int r0 = blockIdx.x * 32, c0 = blockIdx.y * 32;
  const int tx = threadIdx.x, ty = threadIdx.y;  // (32,8)
#pragma unroll
  for (int j = 0; j < 32; j += 8)
    t[ty + j][tx] = src[(long)(r0 + ty + j) * ldi + c0 + tx];
  __syncthreads();
#pragma unroll
  for (int j = 0; j < 32; j += 8)
    dst[(long)(c0 + ty + j) * ldo + r0 + tx] = t[tx][ty + j];
}

// ---------------- 2x2 tile norms^2 for q (tau=0) and k (tau=1) slices of qkv
__global__ __launch_bounds__(256)
void tile_norms(const f16* __restrict__ qkv, float* __restrict__ nq, float* __restrict__ nk) {
  long i = (long)blockIdx.x * 256 + threadIdx.x;  // 4*1024*128 per tensor
  const int tau = blockIdx.y;
  const int d8 = (int)(i & 127);
  const int s2 = (int)((i >> 7) & 1023);
  const int b  = (int)(i >> 17);
  const f16* p0 = qkv + ((long)b * 2048 + 2 * s2) * 3072 + tau * 1024 + d8 * 8;
  f16x8 r0 = *(const f16x8*)p0;
  f16x8 r1 = *(const f16x8*)(p0 + 3072);
  float oo[4];
#pragma unroll
  for (int j = 0; j < 4; j++) {
    float a = (float)r0[2*j], c = (float)r0[2*j+1];
    float d = (float)r1[2*j], e = (float)r1[2*j+1];
    oo[j] = a*a + c*c + d*d + e*e;
  }
  float* dst = (tau ? nk : nq) + ((long)b * 1024 + s2) * 512 + d8 * 4;
  float4 o = {oo[0], oo[1], oo[2], oo[3]};
  *(float4*)dst = o;
}

// ---------------- WO row norms^2 (exact f32): one wave per row of (8192,1024)
__global__ __launch_bounds__(256)
void row_norms(const float* __restrict__ WO, float* __restrict__ wno) {
  const int wid = threadIdx.x >> 6, lane = threadIdx.x & 63;
  const long row = (long)blockIdx.x * 4 + wid;
  const float* p = WO + row * 1024;
  float s = 0.f;
#pragma unroll
  for (int j = 0; j < 4; j++) {
    float4 v = *(const float4*)(p + lane * 4 + j * 256);
    s += v.x*v.x + v.y*v.y + v.z*v.z + v.w*v.w;
  }
  for (int off = 32; off; off >>= 1) s += __shfl_down(s, off, 64);
  if (lane == 0) wno[row] = s;
}

// ---------------- exact radix-select of rank-r value (upper-middle order stat)
__global__ __launch_bounds__(256)
void select_init(unsigned* hist, unsigned* prefix, unsigned* rankrem) {
  int i = blockIdx.x * 256 + threadIdx.x;
  if (i < 12 * 2048) hist[i] = 0;
  if (i < 12) { prefix[i] = 0; rankrem[i] = (i < 8) ? 262144u : 1024u; }
}

__global__ __launch_bounds__(256)
void hist_pass(const float* __restrict__ nq, const float* __restrict__ nk,
               const float* __restrict__ wno, unsigned* __restrict__ hist,
               const unsigned* __restrict__ prefix,
               int shift, int nbins, unsigned himask) {
  __shared__ unsigned lh[2048];
  const int pid = blockIdx.y;
  for (int i = threadIdx.x; i < nbins; i += 256) lh[i] = 0;
  __syncthreads();
  const float* base; long N;
  if (pid < 4)      { base = nq  + (long)pid       * 524288; N = 524288; }
  else if (pid < 8) { base = nk  + (long)(pid - 4) * 524288; N = 524288; }
  else              { base = wno + (long)(pid - 8) * 2048;   N = 2048;  }
  const unsigned pref = prefix[pid];
  long chunk = (N + gridDim.x - 1) / gridDim.x;
  long s = (long)blockIdx.x * chunk;
  long e = s + chunk; if (e > N) e = N;
  for (long i = s + threadIdx.x; i < e; i += 256) {
    unsigned u = __float_as_uint(base[i]);
    if ((u & himask) == pref) atomicAdd(&lh[(u >> shift) & (nbins - 1)], 1u);
  }
  __syncthreads();
  for (int i = threadIdx.x; i < nbins; i += 256)
    if (lh[i]) atomicAdd(&hist[pid * 2048 + i], lh[i]);
}

// Parallel scan: 256 threads each own nbins/256 bins; Hillis-Steele over chunk sums.
__global__ __launch_bounds__(256)
void scan_pass(unsigned* __restrict__ hist, unsigned* __restrict__ prefix,
               unsigned* __restrict__ rankrem, float* __restrict__ thr,
               int shift, int nbins, int final_pass) {
  __shared__ unsigned buf[2][256];
  const int pid = blockIdx.x;
  const int tid = threadIdx.x;
  unsigned* h = hist + pid * 2048;
  const int per = nbins >> 8;  // 8 or 4
  const unsigned r = rankrem[pid];
  const unsigned oldpref = prefix[pid];
  unsigned local[8];
  unsigned s = 0;
#pragma unroll
  for (int j = 0; j < 8; j++) {
    if (j < per) {
      local[j] = h[tid * per + j];
      h[tid * per + j] = 0;
      s += local[j];
    }
  }
  buf[0][tid] = s;
  __syncthreads();
  int src = 0;
#pragma unroll
  for (int d = 1; d < 256; d <<= 1) {
    unsigned v = buf[src][tid];
    if (tid >= d) v += buf[src][tid - d];
    buf[src ^ 1][tid] = v;
    __syncthreads();
    src ^= 1;
  }
  const unsigned incl = buf[src][tid];
  const unsigned excl = incl - s;
  if (excl <= r && r < incl) {
    unsigned accu = excl;
#pragma unroll
    for (int j = 0; j < 8; j++) {
      if (j < per) {
        if (accu + local[j] > r) {
          rankrem[pid] = r - accu;
          unsigned np = oldpref | ((unsigned)(tid * per + j) << shift);
          prefix[pid] = np;
          if (final_pass) thr[pid] = __uint_as_float(np);
          break;
        }
        accu += local[j];
      }
    }
  }
}

// ---------------- apply 2x2-tile mask in place on q/k slices of qkv
__global__ __launch_bounds__(256)
void apply_mask_qk(f16* __restrict__ qkv, const float* __restrict__ nq,
                   const float* __restrict__ nk, const float* __restrict__ thr) {
  long i = (long)blockIdx.x * 256 + threadIdx.x;  // 2^20 per tensor
  const int tau = blockIdx.y;
  const int d8 = (int)(i & 127);
  const int s  = (int)((i >> 7) & 2047);
  const int b  = (int)(i >> 18);
  const float* nrm = (tau ? nk : nq) + ((long)b * 1024 + (s >> 1)) * 512 + d8 * 4;
  const float t = thr[tau * 4 + b];
  f16* p = qkv + ((long)b * 2048 + s) * 3072 + tau * 1024 + d8 * 8;
  f16x8 v = *(f16x8*)p;
  float4 nv = *(const float4*)nrm;
  if (nv.x < t) { v[0] = (f16)0.f; v[1] = (f16)0.f; }
  if (nv.y < t) { v[2] = (f16)0.f; v[3] = (f16)0.f; }
  if (nv.z < t) { v[4] = (f16)0.f; v[5] = (f16)0.f; }
  if (nv.w < t) { v[6] = (f16)0.f; v[7] = (f16)0.f; }
  *(f16x8*)p = v;
}

// ---------------- fused WO row-mask + transpose + f32->f16: WO (b,2048,1024) -> WOT (b,1024,2048)
__global__ __launch_bounds__(256)
void wo_maskT(const float* __restrict__ WO, const float* __restrict__ wno,
              const float* __restrict__ thr, f16* __restrict__ WOT) {
  __shared__ f16 t[32][33];
  const int b = blockIdx.z;
  const int s0 = blockIdx.x * 32, d0 = blockIdx.y * 32;
  const int tx = threadIdx.x, ty = threadIdx.y;  // (32,8)
  const float tb = thr[8 + b];
#pragma unroll
  for (int j = 0; j < 32; j += 8) {
    const int s = s0 + ty + j;
    const float m = (wno[(long)b * 2048 + s] >= tb) ? 1.f : 0.f;
    t[ty + j][tx] = (f16)(WO[((long)b * 2048 + s) * 1024 + d0 + tx] * m);
  }
  __syncthreads();
#pragma unroll
  for (int j = 0; j < 32; j += 8)
    WOT[((long)b * 1024 + d0 + ty + j) * 2048 + s0 + tx] = t[tx][ty + j];
}

extern "C" void kernel_launch(void* const* d_in, const int* in_sizes, int n_in,
                              void* d_out, int out_size, void* d_ws, size_t ws_size,
                              hipStream_t stream) {
  const float* x    = (const float*)d_in[0];   // (4,2048,1024)
  const float* Wqkv = (const float*)d_in[1];   // (3072,1024)
  const float* bqkv = (const float*)d_in[2];   // (3072,)
  const float* WO   = (const float*)d_in[3];   // (4,1,2048,1024)
  float* out = (float*)d_out;                  // (4,2048,1024) f32

  char* w = (char*)d_ws;
  auto alloc = [&](size_t bytes) { char* p = w; w += (bytes + 255) & ~(size_t)255; return p; };
  f16*      xh      = (f16*)alloc(8192L * 1024 * 2);
  f16*      wh      = (f16*)alloc(3072L * 1024 * 2);
  f16*      xT      = (f16*)alloc(4L * 1024 * 2048 * 2);
  f16*      qkv     = (f16*)alloc(8192L * 3072 * 2);
  float*    nq      = (float*)alloc(4L * 524288 * 4);
  float*    nk      = (float*)alloc(4L * 524288 * 4);
  float*    wno     = (float*)alloc(8192L * 4);
  unsigned* hist    = (unsigned*)alloc(12L * 2048 * 4);
  unsigned* prefix  = (unsigned*)alloc(256);
  unsigned* rankrem = (unsigned*)alloc(256);
  float*    thr     = (float*)alloc(256);
  f16*      WOT     = (f16*)alloc(4L * 1024 * 2048 * 2);
  f16*      PqT     = (f16*)alloc(4L * 1024 * 2048 * 2);
  f16*      PkT     = (f16*)alloc(4L * 1024 * 2048 * 2);
  f16*      vT      = (f16*)alloc(4L * 1024 * 2048 * 2);
  f16*      Zt      = (f16*)alloc(4L * 1024 * 1024 * 2);
  f16*      A1      = (f16*)alloc(4L * 1024 * 1024 * 2);
  f16*      B2      = (f16*)alloc(4L * 1024 * 1024 * 2);
  f16*      M1      = (f16*)alloc(4L * 1024 * 1024 * 2);
  f16*      M2T     = (f16*)alloc(4L * 1024 * 1024 * 2);
  if ((size_t)(w - (char*)d_ws) > ws_size) return;  // workspace too small: fail visibly

  // 1. fp16 conversions
  cvt_f32_f16<<<8192, 256, 0, stream>>>(x, xh, 8192L * 1024 / 4);
  cvt_f32_f16<<<3072, 256, 0, stream>>>(Wqkv, wh, 3072L * 1024 / 4);
  // 2. qkv = x @ Wqkv^T + bqkv   (M=8192,N=3072,K=1024)
  gemm_bt<f16, true, false><<<dim3(24, 64, 1), 256, 0, stream>>>(
      xh, wh, qkv, bqkv, 1024, 1024, 1024, 3072, 0, 0, 0, 1.f);
  // 3. xT (per batch 1024x2048)
  transpose_f16<<<dim3(64, 32, 4), dim3(32, 8), 0, stream>>>(
      xh, xT, 1024, 2048, 2048L * 1024, 1024L * 2048);
  // 4. norms
  tile_norms<<<dim3(2048, 2), 256, 0, stream>>>(qkv, nq, nk);
  row_norms<<<2048, 256, 0, stream>>>(WO, wno);
  // 5. exact medians via 3-pass radix select (bits 31:21 / 20:10 / 9:0)
  select_init<<<96, 256, 0, stream>>>(hist, prefix, rankrem);
  hist_pass<<<dim3(32, 12), 256, 0, stream>>>(nq, nk, wno, hist, prefix, 21, 2048, 0u);
  scan_pass<<<12, 256, 0, stream>>>(hist, prefix, rankrem, thr, 21, 2048, 0);
  hist_pass<<<dim3(32, 12), 256, 0, stream>>>(nq, nk, wno, hist, prefix, 10, 2048, 0xFFE00000u);
  scan_pass<<<12, 256, 0, stream>>>(hist, prefix, rankrem, thr, 10, 2048, 0);
  hist_pass<<<dim3(32, 12), 256, 0, stream>>>(nq, nk, wno, hist, prefix, 0, 1024, 0xFFFFFC00u);
  scan_pass<<<12, 256, 0, stream>>>(hist, prefix, rankrem, thr, 0, 1024, 1);
  // 6. masks
  apply_mask_qk<<<dim3(4096, 2), 256, 0, stream>>>(qkv, nq, nk, thr);
  wo_maskT<<<dim3(64, 32, 4), dim3(32, 8), 0, stream>>>(WO, wno, thr, WOT);
  // 7. transposes of masked q,k and of v (all from qkv, per-batch 2048x1024 slices)
  transpose_f16<<<dim3(64, 32, 4), dim3(32, 8), 0, stream>>>(
      qkv, PqT, 3072, 2048, 2048L * 3072, 1024L * 2048);
  transpose_f16<<<dim3(64, 32, 4), dim3(32, 8), 0, stream>>>(
      qkv + 1024, PkT, 3072, 2048, 2048L * 3072, 1024L * 2048);
  transpose_f16<<<dim3(64, 32, 4), dim3(32, 8), 0, stream>>>(
      qkv + 2048, vT, 3072, 2048, 2048L * 3072, 1024L * 2048);
  // 8. reassociated chain: out = x·[Pq^T·Pk]·[x^T·v]·[WO_^T·x]/32
  // stage 1 (merged, 768 blocks): A1 = Pq^T·Pk /32 ; B2 = (x^T·v)^T /32 = v^T·x /32 ;
  //                               Zt = (WO_^T·x)^T /32 = x^T·WO_ /32
  gemm3<<<dim3(8, 8, 12), 256, 0, stream>>>(
      PqT, PkT, A1, vT, xT, B2, xT, WOT, Zt, 0.03125f);
  // stage 2: M1 = A1·(x^T·v)/1024 : C[i,k] = sum_j A1[i,j]·B2[k,j]
  gemm_bt<f16, false, false><<<dim3(8, 8, 4), 256, 0, stream>>>(
      A1, B2, M1, nullptr, 1024, 1024, 1024, 1024,
      1024L * 1024, 1024L * 1024, 1024L * 1024, 1.f);
  // stage 3: M2 = M1·(WO_^T·x), stored transposed with alpha=1/4 -> M2T = P/2^17
  gemm_bt<f16, false, true><<<dim3(8, 8, 4), 256, 0, stream>>>(
      M1, Zt, M2T, nullptr, 1024, 1024, 1024, 1024,
      1024L * 1024, 1024L * 1024, 1024L * 1024, 0.25f);
  // stage 4: out = x·M2 · 4096  (total scale 4096/2^17 = 1/32)
  gemm_bt<float, false, false><<<dim3(8, 16, 4), 256, 0, stream>>>(
      xh, M2T, out, nullptr, 1024, 1024, 1024, 1024,
      2048L * 1024, 1024L * 1024, 2048L * 1024, 4096.f);
}

// Round 4
// 362.136 us; speedup vs baseline: 1.9155x; 1.0810x over previous
//
#include <hip/hip_runtime.h>

typedef _Float16 f16;
typedef _Float16 f16x8 __attribute__((ext_vector_type(8)));
typedef _Float16 f16x4 __attribute__((ext_vector_type(4)));
typedef float f32x4 __attribute__((ext_vector_type(4)));

__device__ __forceinline__ void gload16(const void* g, void* l) {
  __builtin_amdgcn_global_load_lds(
      (const __attribute__((address_space(1))) void*)g,
      (__attribute__((address_space(3))) void*)l, 16, 0, 0);
}

#define SCHED_FENCE __builtin_amdgcn_sched_barrier(0)
#define RAW_BARRIER do { SCHED_FENCE; __builtin_amdgcn_s_barrier(); SCHED_FENCE; } while (0)
#define WAIT_LGKM0  do { asm volatile("s_waitcnt lgkmcnt(0)" ::: "memory"); SCHED_FENCE; } while (0)
#define WAIT_VM(n)  do { asm volatile("s_waitcnt vmcnt(" #n ")" ::: "memory"); SCHED_FENCE; } while (0)

// ================= 256x256-tile GEMM, BK=32, 4-deep LDS pipeline, counted vmcnt =============
// C = alpha * A(M,K) * B(N,K)^T [+ bias]. 512 threads = 8 waves (2M x 4N), per-wave 128x64
// output = 8x4 frags of 16x16x32 f16 MFMA. LDS: 4 buffers x (A 16KB + B 16KB) = 128 KiB;
// prefetch distance 3 K-tiles; ONE raw s_barrier per K-tile; vmcnt(8) steady-state (never 0
// until drain). LDS granule permutation: logical (row r, col-granule c4) at granule
// (r>>4)*64 + (r&15)*4 + (c4 ^ ((r>>1)&3)) -> a frag-read's 16 lanes (rows r0..r0+15, c4
// fixed) land on all 8 bank-groups exactly twice = conflict-free. global_load_lds writes
// linearly (wave base + lane*16B), so the SOURCE address carries the inverse permutation.
template<bool BIAS>
__device__ __forceinline__ void gemm256_body(
    const f16* __restrict__ A, const f16* __restrict__ B, f16* __restrict__ C,
    const float* __restrict__ bias, int K, int lda, int ldb, int ldc, float alpha,
    f16* lds)
{
  const int NT = K >> 5;                       // K-tiles of 32
  const int brow = blockIdx.y << 8;
  const int bcol = blockIdx.x << 8;
  const int tid = threadIdx.x;
  const int lane = tid & 63;
  const int wid = tid >> 6;
  const int wr = wid >> 2;                     // 0..1  (M half)
  const int wc = wid & 3;                      // 0..3  (N quarter)
  const int fr = lane & 15;
  const int kq = lane >> 4;

  // staging: per K-tile each thread issues 2 A-loads + 2 B-loads; load i covers LDS granule
  // p = wid*128 + i*64 + lane (wave-uniform base + lane*16B, as global_load_lds requires).
  const f16* pA[2]; const f16* pB[2]; int pdst[2];
#pragma unroll
  for (int i = 0; i < 2; i++) {
    const int p = wid * 128 + i * 64 + lane;
    const int rr = ((p >> 6) << 4) | ((p >> 2) & 15);      // logical row
    const int c4 = (p & 3) ^ ((p >> 3) & 3);               // logical col-granule (inverse swz)
    pA[i] = A + (long)(brow + rr) * lda + c4 * 8;
    pB[i] = B + (long)(bcol + rr) * ldb + c4 * 8;
    pdst[i] = p * 8;
  }

  auto STAGE = [&](int t) {
    f16* base = lds + (t & 3) * 16384;
    const int off = t * 32;
#pragma unroll
    for (int i = 0; i < 2; i++) {
      gload16(pA[i] + off, base + pdst[i]);
      gload16(pB[i] + off, base + 8192 + pdst[i]);
    }
  };

  STAGE(0); STAGE(1); STAGE(2);    // 12 loads in flight
  WAIT_VM(8);                      // tile 0 landed
  RAW_BARRIER;

  const int aoff0 = fr * 4 + (kq ^ ((fr >> 1) & 3));       // read-side swizzle
  f32x4 acc[8][4] = {};

#pragma unroll 1
  for (int t = 0; t < NT; ++t) {
    if (t + 3 < NT) STAGE(t + 3);
    const f16* base = lds + (t & 3) * 16384;
    f16x8 av[8], bv[4];
#pragma unroll
    for (int m = 0; m < 8; m++)
      av[m] = *(const f16x8*)(base + ((wr * 8 + m) * 64 + aoff0) * 8);
#pragma unroll
    for (int n = 0; n < 4; n++)
      bv[n] = *(const f16x8*)(base + 8192 + ((wc * 4 + n) * 64 + aoff0) * 8);
    __builtin_amdgcn_s_setprio(1);
#pragma unroll
    for (int m = 0; m < 8; m++)
#pragma unroll
      for (int n = 0; n < 4; n++)
        acc[m][n] = __builtin_amdgcn_mfma_f32_16x16x32_f16(av[m], bv[n], acc[m][n], 0, 0, 0);
    __builtin_amdgcn_s_setprio(0);
    WAIT_LGKM0;                    // all ds_reads of tile t retired (buf safe to overwrite)
    if (t + 4 < NT)      { WAIT_VM(8); }   // tiles t+2,t+3 may stay in flight
    else if (t + 3 < NT) { WAIT_VM(4); }   // drain: only t+2 in flight
    else if (t + 2 < NT) { WAIT_VM(0); }   // drain: last prefetch
    RAW_BARRIER;                   // all waves done with tile t; tile t+1 visible to all
  }

#pragma unroll
  for (int m = 0; m < 8; m++) {
    const int row0 = brow + wr * 128 + m * 16 + kq * 4;
#pragma unroll
    for (int n = 0; n < 4; n++) {
      const int col = bcol + wc * 64 + n * 16 + fr;
      float bb = 0.f;
      if constexpr (BIAS) bb = bias[col];
#pragma unroll
      for (int i = 0; i < 4; i++)
        C[(long)(row0 + i) * ldc + col] = (f16)(acc[m][n][i] * alpha + bb);
    }
  }
}

__global__ __launch_bounds__(512, 2)
void gemm256_qkv(const f16* __restrict__ A, const f16* __restrict__ B, f16* __restrict__ C,
                 const float* __restrict__ bias) {
  __shared__ f16 lds[65536];
  gemm256_body<true>(A, B, C, bias, 1024, 1024, 1024, 3072, 1.f, lds);
}

// merged stage-1: 3 independent 1024x1024 (K=2048) products x 4 batches, blockIdx.z = p*4+b
__global__ __launch_bounds__(512, 2)
void gemm3_256(const f16* __restrict__ Aa, const f16* __restrict__ Ba, f16* __restrict__ Ca,
               const f16* __restrict__ Ab, const f16* __restrict__ Bb, f16* __restrict__ Cb,
               const f16* __restrict__ Ac, const f16* __restrict__ Bc, f16* __restrict__ Cc,
               float alpha) {
  __shared__ f16 lds[65536];
  const int p = blockIdx.z >> 2, b = blockIdx.z & 3;
  const f16* A; const f16* B; f16* C;
  if (p == 0)      { A = Aa; B = Ba; C = Ca; }
  else if (p == 1) { A = Ab; B = Bb; C = Cb; }
  else             { A = Ac; B = Bc; C = Cc; }
  A += (long)b * (1024L * 2048);
  B += (long)b * (1024L * 2048);
  C += (long)b * (1024L * 1024);
  gemm256_body<false>(A, B, C, nullptr, 2048, 2048, 2048, 1024, alpha, lds);
}

// ================= 128x128 GEMM (verified R3 kernel) for the small chain stages ============
template<typename OutT, bool BIAS, bool TRANSC>
__device__ __forceinline__ void gemm_body(
    const f16* __restrict__ A, const f16* __restrict__ B,
    OutT* __restrict__ C, const float* __restrict__ bias,
    int K, int lda, int ldb, int ldc, float alpha,
    f16* lA, f16* lB)
{
  const int brow = blockIdx.y << 7;
  const int bcol = blockIdx.x << 7;
  const int tid = threadIdx.x;
  const int lane = tid & 63;
  const int wid = tid >> 6;
  const int wr = (wid >> 1) << 6;
  const int wc = (wid & 1) << 6;
  const int fr = lane & 15;
  const int kq = lane >> 4;
  const int kqsw = kq ^ ((fr >> 1) & 3);

  const int srow = tid >> 2;
  const int skq  = (tid & 3) ^ ((tid >> 3) & 3);
  const f16* gA0 = A + (long)(brow + srow) * lda + skq * 8;
  const f16* gA1 = A + (long)(brow + 64 + srow) * lda + skq * 8;
  const f16* gB0 = B + (long)(bcol + srow) * ldb + skq * 8;
  const f16* gB1 = B + (long)(bcol + 64 + srow) * ldb + skq * 8;
  f16* lAd0 = &lA[tid * 8];
  f16* lAd1 = &lA[2048 + tid * 8];
  f16* lBd0 = &lB[tid * 8];
  f16* lBd1 = &lB[2048 + tid * 8];

  f32x4 acc[4][4] = {};

  for (int t = 0; t < K; t += 32) {
    gload16(gA0 + t, lAd0);
    gload16(gA1 + t, lAd1);
    gload16(gB0 + t, lBd0);
    gload16(gB1 + t, lBd1);
    __syncthreads();
    f16x8 av[4], bv[4];
#pragma unroll
    for (int m = 0; m < 4; m++)
      av[m] = *(const f16x8*)&lA[(wr + m * 16 + fr) * 32 + kqsw * 8];
#pragma unroll
    for (int n = 0; n < 4; n++)
      bv[n] = *(const f16x8*)&lB[(wc + n * 16 + fr) * 32 + kqsw * 8];
#pragma unroll
    for (int m = 0; m < 4; m++)
#pragma unroll
      for (int n = 0; n < 4; n++)
        acc[m][n] = __builtin_amdgcn_mfma_f32_16x16x32_f16(av[m], bv[n], acc[m][n], 0, 0, 0);
    __syncthreads();
  }

#pragma unroll
  for (int m = 0; m < 4; m++)
#pragma unroll
    for (int n = 0; n < 4; n++) {
      const int row0 = brow + wr + m * 16 + kq * 4;
      const int col  = bcol + wc + n * 16 + fr;
      if constexpr (TRANSC) {
        f16x4 v;
#pragma unroll
        for (int i = 0; i < 4; i++) v[i] = (f16)(acc[m][n][i] * alpha);
        *(f16x4*)&C[(long)col * ldc + row0] = v;
      } else {
        float bb = 0.f;
        if constexpr (BIAS) bb = bias[col];
#pragma unroll
        for (int i = 0; i < 4; i++)
          C[(long)(row0 + i) * ldc + col] = (OutT)(acc[m][n][i] * alpha + bb);
      }
    }
}

template<typename OutT, bool BIAS, bool TRANSC>
__global__ __launch_bounds__(256)
void gemm_bt(const f16* __restrict__ A, const f16* __restrict__ B,
             OutT* __restrict__ C, const float* __restrict__ bias,
             int K, int lda, int ldb, int ldc,
             long sA, long sB, long sC, float alpha)
{
  __shared__ f16 lA[128*32];
  __shared__ f16 lB[128*32];
  const int bz = blockIdx.z;
  gemm_body<OutT, BIAS, TRANSC>(A + bz * sA, B + bz * sB, C + bz * sC, bias,
                                K, lda, ldb, ldc, alpha, lA, lB);
}

// ---------------- f32 -> f16 convert (vectorized x4)
__global__ __launch_bounds__(256)
void cvt_f32_f16(const float* __restrict__ in, f16* __restrict__ out, long n4) {
  long i = (long)blockIdx.x * 256 + threadIdx.x;
  if (i >= n4) return;
  float4 v = ((const float4*)in)[i];
  f16x4 o = {(f16)v.x, (f16)v.y, (f16)v.z, (f16)v.w};
  ((f16x4*)out)[i] = o;
}

// ---------------- fused x: f32 -> (xh f16, xT f16 transposed) in one pass
__global__ __launch_bounds__(256)
void cvtT_x(const float* __restrict__ x, f16* __restrict__ xh, f16* __restrict__ xT) {
  __shared__ f16 t[32][33];
  const int b = blockIdx.z;
  const int s0 = blockIdx.x * 32, d0 = blockIdx.y * 32;
  const int tx = threadIdx.x, ty = threadIdx.y;  // (32,8)
#pragma unroll
  for (int j = 0; j < 32; j += 8) {
    const long idx = ((long)b * 2048 + s0 + ty + j) * 1024 + d0 + tx;
    f16 h = (f16)x[idx];
    xh[idx] = h;
    t[ty + j][tx] = h;
  }
  __syncthreads();
#pragma unroll
  for (int j = 0; j < 32; j += 8)
    xT[((long)b * 1024 + d0 + ty + j) * 2048 + s0 + tx] = t[tx][ty + j];
}

// ---------------- fused masked transposes of q,k and plain transpose of v
// z = tau*4 + b; tau: 0 -> PqT (masked), 1 -> PkT (masked), 2 -> vT (plain)
__global__ __launch_bounds__(256)
void qkvT(const f16* __restrict__ qkv, const float* __restrict__ nq,
          const float* __restrict__ nk, const float* __restrict__ thr,
          f16* __restrict__ PqT, f16* __restrict__ PkT, f16* __restrict__ vT) {
  __shared__ f16 t[32][33];
  const int z = blockIdx.z, tau = z >> 2, b = z & 3;
  f16* dst = (tau == 0) ? PqT : (tau == 1) ? PkT : vT;
  const f16* src = qkv + (long)b * 2048 * 3072 + tau * 1024;
  const int s0 = blockIdx.x * 32, d0 = blockIdx.y * 32;
  const int tx = threadIdx.x, ty = threadIdx.y;  // (32,8)
  if (tau < 2) {
    const float* nrm = (tau ? nk : nq) + (long)b * 1024 * 512;
    const float tb = thr[tau * 4 + b];
#pragma unroll
    for (int j = 0; j < 32; j += 8) {
      const int s = s0 + ty + j, d = d0 + tx;
      f16 v = src[(long)s * 3072 + d];
      t[ty + j][tx] = (nrm[(long)(s >> 1) * 512 + (d >> 1)] >= tb) ? v : (f16)0.f;
    }
  } else {
#pragma unroll
    for (int j = 0; j < 32; j += 8)
      t[ty + j][tx] = src[(long)(s0 + ty + j) * 3072 + d0 + tx];
  }
  __syncthreads();
#pragma unroll
  for (int j = 0; j < 32; j += 8)
    dst[((long)b * 1024 + d0 + ty + j) * 2048 + s0 + tx] = t[tx][ty + j];
}

// ---------------- 2x2 tile norms^2 for q (tau=0) and k (tau=1) slices of qkv
__global__ __launch_bounds__(256)
void tile_norms(const f16* __restrict__ qkv, float* __restrict__ nq, float* __restrict__ nk) {
  long i = (long)blockIdx.x * 256 + threadIdx.x;  // 4*1024*128 per tensor
  const int tau = blockIdx.y;
  const int d8 = (int)(i & 127);
  const int s2 = (int)((i >> 7) & 1023);
  const int b  = (int)(i >> 17);
  const f16* p0 = qkv + ((long)b * 2048 + 2 * s2) * 3072 + tau * 1024 + d8 * 8;
  f16x8 r0 = *(const f16x8*)p0;
  f16x8 r1 = *(const f16x8*)(p0 + 3072);
  float oo[4];
#pragma unroll
  for (int j = 0; j < 4; j++) {
    float a = (float)r0[2*j], c = (float)r0[2*j+1];
    float d = (float)r1[2*j], e = (float)r1[2*j+1];
    oo[j] = a*a + c*c + d*d + e*e;
  }
  float* dst = (tau ? nk : nq) + ((long)b * 1024 + s2) * 512 + d8 * 4;
  float4 o = {oo[0], oo[1], oo[2], oo[3]};
  *(float4*)dst = o;
}

// ---------------- WO row norms^2 (exact f32): one wave per row of (8192,1024)
__global__ __launch_bounds__(256)
void row_norms(const float* __restrict__ WO, float* __restrict__ wno) {
  const int wid = threadIdx.x >> 6, lane = threadIdx.x & 63;
  const long row = (long)blockIdx.x * 4 + wid;
  const float* p = WO + row * 1024;
  float s = 0.f;
#pragma unroll
  for (int j = 0; j < 4; j++) {
    float4 v = *(const float4*)(p + lane * 4 + j * 256);
    s += v.x*v.x + v.y*v.y + v.z*v.z + v.w*v.w;
  }
  for (int off = 32; off; off >>= 1) s += __shfl_down(s, off, 64);
  if (lane == 0) wno[row] = s;
}

// ---------------- exact radix-select of rank-r value (upper-middle order stat)
__global__ __launch_bounds__(256)
void select_init(unsigned* hist, unsigned* prefix, unsigned* rankrem) {
  int i = blockIdx.x * 256 + threadIdx.x;
  if (i < 12 * 2048) hist[i] = 0;
  if (i < 12) { prefix[i] = 0; rankrem[i] = (i < 8) ? 262144u : 1024u; }
}

__global__ __launch_bounds__(256)
void hist_pass(const float* __restrict__ nq, const float* __restrict__ nk,
               const float* __restrict__ wno, unsigned* __restrict__ hist,
               const unsigned* __restrict__ prefix,
               int shift, int nbins, unsigned himask) {
  __shared__ unsigned lh[2048];
  const int pid = blockIdx.y;
  for (int i = threadIdx.x; i < nbins; i += 256) lh[i] = 0;
  __syncthreads();
  const float* base; long N;
  if (pid < 4)      { base = nq  + (long)pid       * 524288; N = 524288; }
  else if (pid < 8) { base = nk  + (long)(pid - 4) * 524288; N = 524288; }
  else              { base = wno + (long)(pid - 8) * 2048;   N = 2048;  }
  const unsigned pref = prefix[pid];
  long chunk = (N + gridDim.x - 1) / gridDim.x;
  long s = (long)blockIdx.x * chunk;
  long e = s + chunk; if (e > N) e = N;
  for (long i = s + threadIdx.x; i < e; i += 256) {
    unsigned u = __float_as_uint(base[i]);
    if ((u & himask) == pref) atomicAdd(&lh[(u >> shift) & (nbins - 1)], 1u);
  }
  __syncthreads();
  for (int i = threadIdx.x; i < nbins; i += 256)
    if (lh[i]) atomicAdd(&hist[pid * 2048 + i], lh[i]);
}

// Parallel scan: 256 threads each own nbins/256 bins; Hillis-Steele over chunk sums.
__global__ __launch_bounds__(256)
void scan_pass(unsigned* __restrict__ hist, unsigned* __restrict__ prefix,
               unsigned* __restrict__ rankrem, float* __restrict__ thr,
               int shift, int nbins, int final_pass) {
  __shared__ unsigned buf[2][256];
  const int pid = blockIdx.x;
  const int tid = threadIdx.x;
  unsigned* h = hist + pid * 2048;
  const int per = nbins >> 8;  // 8 or 4
  const unsigned r = rankrem[pid];
  const unsigned oldpref = prefix[pid];
  unsigned local[8];
  unsigned s = 0;
#pragma unroll
  for (int j = 0; j < 8; j++) {
    if (j < per) {
      local[j] = h[tid * per + j];
      h[tid * per + j] = 0;
      s += local[j];
    }
  }
  buf[0][tid] = s;
  __syncthreads();
  int src = 0;
#pragma unroll
  for (int d = 1; d < 256; d <<= 1) {
    unsigned v = buf[src][tid];
    if (tid >= d) v += buf[src][tid - d];
    buf[src ^ 1][tid] = v;
    __syncthreads();
    src ^= 1;
  }
  const unsigned incl = buf[src][tid];
  const unsigned excl = incl - s;
  if (excl <= r && r < incl) {
    unsigned accu = excl;
#pragma unroll
    for (int j = 0; j < 8; j++) {
      if (j < per) {
        if (accu + local[j] > r) {
          rankrem[pid] = r - accu;
          unsigned np = oldpref | ((unsigned)(tid * per + j) << shift);
          prefix[pid] = np;
          if (final_pass) thr[pid] = __uint_as_float(np);
          break;
        }
        accu += local[j];
      }
    }
  }
}

// ---------------- fused WO row-mask + transpose + f32->f16: WO (b,2048,1024) -> WOT (b,1024,2048)
__global__ __launch_bounds__(256)
void wo_maskT(const float* __restrict__ WO, const float* __restrict__ wno,
              const float* __restrict__ thr, f16* __restrict__ WOT) {
  __shared__ f16 t[32][33];
  const int b = blockIdx.z;
  const int s0 = blockIdx.x * 32, d0 = blockIdx.y * 32;
  const int tx = threadIdx.x, ty = threadIdx.y;  // (32,8)
  const float tb = thr[8 + b];
#pragma unroll
  for (int j = 0; j < 32; j += 8) {
    const int s = s0 + ty + j;
    const float m = (wno[(long)b * 2048 + s] >= tb) ? 1.f : 0.f;
    t[ty + j][tx] = (f16)(WO[((long)b * 2048 + s) * 1024 + d0 + tx] * m);
  }
  __syncthreads();
#pragma unroll
  for (int j = 0; j < 32; j += 8)
    WOT[((long)b * 1024 + d0 + ty + j) * 2048 + s0 + tx] = t[tx][ty + j];
}

extern "C" void kernel_launch(void* const* d_in, const int* in_sizes, int n_in,
                              void* d_out, int out_size, void* d_ws, size_t ws_size,
                              hipStream_t stream) {
  const float* x    = (const float*)d_in[0];   // (4,2048,1024)
  const float* Wqkv = (const float*)d_in[1];   // (3072,1024)
  const float* bqkv = (const float*)d_in[2];   // (3072,)
  const float* WO   = (const float*)d_in[3];   // (4,1,2048,1024)
  float* out = (float*)d_out;                  // (4,2048,1024) f32

  char* w = (char*)d_ws;
  auto alloc = [&](size_t bytes) { char* p = w; w += (bytes + 255) & ~(size_t)255; return p; };
  f16*      xh      = (f16*)alloc(8192L * 1024 * 2);
  f16*      wh      = (f16*)alloc(3072L * 1024 * 2);
  f16*      xT      = (f16*)alloc(4L * 1024 * 2048 * 2);
  f16*      qkv     = (f16*)alloc(8192L * 3072 * 2);
  float*    nq      = (float*)alloc(4L * 524288 * 4);
  float*    nk      = (float*)alloc(4L * 524288 * 4);
  float*    wno     = (float*)alloc(8192L * 4);
  unsigned* hist    = (unsigned*)alloc(12L * 2048 * 4);
  unsigned* prefix  = (unsigned*)alloc(256);
  unsigned* rankrem = (unsigned*)alloc(256);
  float*    thr     = (float*)alloc(256);
  f16*      WOT     = (f16*)alloc(4L * 1024 * 2048 * 2);
  f16*      PqT     = (f16*)alloc(4L * 1024 * 2048 * 2);
  f16*      PkT     = (f16*)alloc(4L * 1024 * 2048 * 2);
  f16*      vT      = (f16*)alloc(4L * 1024 * 2048 * 2);
  f16*      Zt      = (f16*)alloc(4L * 1024 * 1024 * 2);
  f16*      A1      = (f16*)alloc(4L * 1024 * 1024 * 2);
  f16*      B2      = (f16*)alloc(4L * 1024 * 1024 * 2);
  f16*      M1      = (f16*)alloc(4L * 1024 * 1024 * 2);
  f16*      M2T     = (f16*)alloc(4L * 1024 * 1024 * 2);
  if ((size_t)(w - (char*)d_ws) > ws_size) return;  // workspace too small: fail visibly

  // 1. conversions: x -> (xh, xT) fused; Wqkv -> wh
  cvtT_x<<<dim3(64, 32, 4), dim3(32, 8), 0, stream>>>(x, xh, xT);
  cvt_f32_f16<<<3072, 256, 0, stream>>>(Wqkv, wh, 3072L * 1024 / 4);
  // 2. qkv = x @ Wqkv^T + bqkv  (M=8192,N=3072,K=1024), 256^2 pipelined GEMM
  gemm256_qkv<<<dim3(12, 32, 1), 512, 0, stream>>>(xh, wh, qkv, bqkv);
  // 3. norms
  tile_norms<<<dim3(2048, 2), 256, 0, stream>>>(qkv, nq, nk);
  row_norms<<<2048, 256, 0, stream>>>(WO, wno);
  // 4. exact medians via 3-pass radix select (bits 31:21 / 20:10 / 9:0)
  select_init<<<96, 256, 0, stream>>>(hist, prefix, rankrem);
  hist_pass<<<dim3(32, 12), 256, 0, stream>>>(nq, nk, wno, hist, prefix, 21, 2048, 0u);
  scan_pass<<<12, 256, 0, stream>>>(hist, prefix, rankrem, thr, 21, 2048, 0);
  hist_pass<<<dim3(32, 12), 256, 0, stream>>>(nq, nk, wno, hist, prefix, 10, 2048, 0xFFE00000u);
  scan_pass<<<12, 256, 0, stream>>>(hist, prefix, rankrem, thr, 10, 2048, 0);
  hist_pass<<<dim3(32, 12), 256, 0, stream>>>(nq, nk, wno, hist, prefix, 0, 1024, 0xFFFFFC00u);
  scan_pass<<<12, 256, 0, stream>>>(hist, prefix, rankrem, thr, 0, 1024, 1);
  // 5. masked transposes (mask fused into transpose read) + WO mask-transpose
  qkvT<<<dim3(64, 32, 12), dim3(32, 8), 0, stream>>>(qkv, nq, nk, thr, PqT, PkT, vT);
  wo_maskT<<<dim3(64, 32, 4), dim3(32, 8), 0, stream>>>(WO, wno, thr, WOT);
  // 6. reassociated chain: out = x·[Pq^T·Pk]·[x^T·v]·[WO_^T·x]/32
  // stage 1 (merged, 192 blocks, 256^2 pipelined): A1 = Pq^T·Pk/32 ; B2 = v^T·x/32 ; Zt = x^T·WO_/32
  gemm3_256<<<dim3(4, 4, 12), 512, 0, stream>>>(
      PqT, PkT, A1, vT, xT, B2, xT, WOT, Zt, 0.03125f);
  // stage 2: M1 = A1·B2^T
  gemm_bt<f16, false, false><<<dim3(8, 8, 4), 256, 0, stream>>>(
      A1, B2, M1, nullptr, 1024, 1024, 1024, 1024,
      1024L * 1024, 1024L * 1024, 1024L * 1024, 1.f);
  // stage 3: M2T = (M1·Zt^T)^T / 4
  gemm_bt<f16, false, true><<<dim3(8, 8, 4), 256, 0, stream>>>(
      M1, Zt, M2T, nullptr, 1024, 1024, 1024, 1024,
      1024L * 1024, 1024L * 1024, 1024L * 1024, 0.25f);
  // stage 4: out = x·M2 · 4096  (total scale 4096/2^17 = 1/32)
  gemm_bt<float, false, false><<<dim3(8, 16, 4), 256, 0, stream>>>(
      xh, M2T, out, nullptr, 1024, 1024, 1024, 1024,
      2048L * 1024, 1024L * 1024, 2048L * 1024, 4096.f);
}

// Round 5
// 355.963 us; speedup vs baseline: 1.9487x; 1.0173x over previous
//
#include <hip/hip_runtime.h>

typedef _Float16 f16;
typedef _Float16 f16x8 __attribute__((ext_vector_type(8)));
typedef _Float16 f16x4 __attribute__((ext_vector_type(4)));
typedef float f32x4 __attribute__((ext_vector_type(4)));

__device__ __forceinline__ void gload16(const void* g, void* l) {
  __builtin_amdgcn_global_load_lds(
      (const __attribute__((address_space(1))) void*)g,
      (__attribute__((address_space(3))) void*)l, 16, 0, 0);
}

#define SCHED_FENCE __builtin_amdgcn_sched_barrier(0)
#define RAW_BARRIER do { SCHED_FENCE; __builtin_amdgcn_s_barrier(); SCHED_FENCE; } while (0)
#define WAIT_VM_0    do { asm volatile("s_waitcnt vmcnt(0)"     ::: "memory"); SCHED_FENCE; } while (0)
#define WAIT_VM_4    do { asm volatile("s_waitcnt vmcnt(4)"     ::: "memory"); SCHED_FENCE; } while (0)
#define WAIT_LGKM_0  do { asm volatile("s_waitcnt lgkmcnt(0)"   ::: "memory"); SCHED_FENCE; } while (0)
#define WAIT_LGKM_12 do { asm volatile("s_waitcnt lgkmcnt(12)"  ::: "memory"); SCHED_FENCE; } while (0)

// ================= 256x256-tile GEMM, BK=32, 4-deep LDS pipeline =====================
// C = alpha * A(M,K) * B(N,K)^T [+ bias]. 512 threads = 8 waves (2M x 4N), per-wave 128x64.
// NEW vs R4: register double-buffer of LDS fragments. Iter t issues the 12 ds_read_b128
// for tile t+1 BEFORE the MFMA cluster on tile t's regs; counted lgkmcnt(12) retires the
// PREVIOUS iter's reads only -> ds_read executes under the matrix pipe instead of on the
// critical path. vmcnt gate ensures tile t+2 landed (read next iter): steady vmcnt(4),
// never 0 until drain. Safety: tile t+1 reads happen >=1 barrier after its landing gate
// (iter t-1 vm(4)+barrier); buf[(t+1)&3] overwritten only by STAGE(t+5) at iter t+2,
// >=1 barrier after those reads retire (iter t+1 lgkm gate).
// LDS granule permutation (both-sides, rule 21): logical (row r, col-granule c4) at granule
// (r>>4)*64 + (r&15)*4 + (c4 ^ ((r>>1)&3)); 16-lane frag reads hit all 8 bank-groups x2.
template<bool BIAS>
__device__ __forceinline__ void gemm256_body(
    const f16* __restrict__ A, const f16* __restrict__ B, f16* __restrict__ C,
    const float* __restrict__ bias, int K, int lda, int ldb, int ldc, float alpha,
    f16* lds)
{
  const int NT = K >> 5;                       // K-tiles of 32 (always even here)
  const int brow = blockIdx.y << 8;
  const int bcol = blockIdx.x << 8;
  const int tid = threadIdx.x;
  const int lane = tid & 63;
  const int wid = tid >> 6;
  const int wr = wid >> 2;                     // 0..1  (M half)
  const int wc = wid & 3;                      // 0..3  (N quarter)
  const int fr = lane & 15;
  const int kq = lane >> 4;

  const f16* pA[2]; const f16* pB[2]; int pdst[2];
#pragma unroll
  for (int i = 0; i < 2; i++) {
    const int p = wid * 128 + i * 64 + lane;
    const int rr = ((p >> 6) << 4) | ((p >> 2) & 15);      // logical row
    const int c4 = (p & 3) ^ ((p >> 3) & 3);               // inverse-swizzled col-granule
    pA[i] = A + (long)(brow + rr) * lda + c4 * 8;
    pB[i] = B + (long)(bcol + rr) * ldb + c4 * 8;
    pdst[i] = p * 8;
  }

  auto STAGE = [&](int t) {
    f16* base = lds + (t & 3) * 16384;
    const int off = t * 32;
#pragma unroll
    for (int i = 0; i < 2; i++) {
      gload16(pA[i] + off, base + pdst[i]);
      gload16(pB[i] + off, base + 8192 + pdst[i]);
    }
  };

  const int aoff0 = fr * 4 + (kq ^ ((fr >> 1) & 3));       // read-side swizzle
  f32x4 acc[8][4] = {};
  f16x8 avA[8], bvA[4], avB[8], bvB[4];

  STAGE(0); STAGE(1); STAGE(2);    // 12 loads in flight
  WAIT_VM_4;                       // tiles 0 AND 1 landed (iter 0 prefetches tile 1)
  RAW_BARRIER;
#pragma unroll
  for (int m = 0; m < 8; m++)
    avA[m] = *(const f16x8*)(lds + ((wr * 8 + m) * 64 + aoff0) * 8);
#pragma unroll
  for (int n = 0; n < 4; n++)
    bvA[n] = *(const f16x8*)(lds + 8192 + ((wc * 4 + n) * 64 + aoff0) * 8);

#define GEMM_ITER(T, AVC, BVC, AVN, BVN)                                        \
  do {                                                                          \
    if ((T) + 3 < NT) STAGE((T) + 3);                                           \
    if ((T) + 1 < NT) {                                                         \
      const f16* nb_ = lds + (((T) + 1) & 3) * 16384;                           \
      _Pragma("unroll")                                                         \
      for (int m = 0; m < 8; m++)                                               \
        AVN[m] = *(const f16x8*)(nb_ + ((wr * 8 + m) * 64 + aoff0) * 8);        \
      _Pragma("unroll")                                                         \
      for (int n = 0; n < 4; n++)                                               \
        BVN[n] = *(const f16x8*)(nb_ + 8192 + ((wc * 4 + n) * 64 + aoff0) * 8); \
      WAIT_LGKM_12;   /* prev iter's 12 reads retired; these 12 stay in flight */\
    } else {                                                                    \
      WAIT_LGKM_0;    /* last iter: no new reads issued to count against */     \
    }                                                                           \
    __builtin_amdgcn_s_setprio(1);                                              \
    _Pragma("unroll")                                                           \
    for (int m = 0; m < 8; m++)                                                 \
      _Pragma("unroll")                                                         \
      for (int n = 0; n < 4; n++)                                               \
        acc[m][n] = __builtin_amdgcn_mfma_f32_16x16x32_f16(AVC[m], BVC[n],      \
                                                           acc[m][n], 0, 0, 0); \
    __builtin_amdgcn_s_setprio(0);                                              \
    if ((T) + 3 < NT)      { WAIT_VM_4; }  /* tile T+2 landed for next iter */  \
    else if ((T) + 2 < NT) { WAIT_VM_0; }  /* drain: last outstanding stage */  \
    RAW_BARRIER;                                                                \
  } while (0)

#pragma unroll 1
  for (int t = 0; t < NT; t += 2) {
    GEMM_ITER(t,     avA, bvA, avB, bvB);
    GEMM_ITER(t + 1, avB, bvB, avA, bvA);
  }
#undef GEMM_ITER

#pragma unroll
  for (int m = 0; m < 8; m++) {
    const int row0 = brow + wr * 128 + m * 16 + kq * 4;
#pragma unroll
    for (int n = 0; n < 4; n++) {
      const int col = bcol + wc * 64 + n * 16 + fr;
      float bb = 0.f;
      if constexpr (BIAS) bb = bias[col];
#pragma unroll
      for (int i = 0; i < 4; i++)
        C[(long)(row0 + i) * ldc + col] = (f16)(acc[m][n][i] * alpha + bb);
    }
  }
}

__global__ __launch_bounds__(512, 2)
void gemm256_qkv(const f16* __restrict__ A, const f16* __restrict__ B, f16* __restrict__ C,
                 const float* __restrict__ bias) {
  __shared__ f16 lds[65536];
  gemm256_body<true>(A, B, C, bias, 1024, 1024, 1024, 3072, 1.f, lds);
}

// merged stage-1: 3 independent 1024x1024 (K=2048) products x 4 batches, blockIdx.z = p*4+b
__global__ __launch_bounds__(512, 2)
void gemm3_256(const f16* __restrict__ Aa, const f16* __restrict__ Ba, f16* __restrict__ Ca,
               const f16* __restrict__ Ab, const f16* __restrict__ Bb, f16* __restrict__ Cb,
               const f16* __restrict__ Ac, const f16* __restrict__ Bc, f16* __restrict__ Cc,
               float alpha) {
  __shared__ f16 lds[65536];
  const int p = blockIdx.z >> 2, b = blockIdx.z & 3;
  const f16* A; const f16* B; f16* C;
  if (p == 0)      { A = Aa; B = Ba; C = Ca; }
  else if (p == 1) { A = Ab; B = Bb; C = Cb; }
  else             { A = Ac; B = Bc; C = Cc; }
  A += (long)b * (1024L * 2048);
  B += (long)b * (1024L * 2048);
  C += (long)b * (1024L * 1024);
  gemm256_body<false>(A, B, C, nullptr, 2048, 2048, 2048, 1024, alpha, lds);
}

// ================= 128x128 GEMM (verified) for the small chain stages ============
template<typename OutT, bool BIAS, bool TRANSC>
__device__ __forceinline__ void gemm_body(
    const f16* __restrict__ A, const f16* __restrict__ B,
    OutT* __restrict__ C, const float* __restrict__ bias,
    int K, int lda, int ldb, int ldc, float alpha,
    f16* lA, f16* lB)
{
  const int brow = blockIdx.y << 7;
  const int bcol = blockIdx.x << 7;
  const int tid = threadIdx.x;
  const int lane = tid & 63;
  const int wid = tid >> 6;
  const int wr = (wid >> 1) << 6;
  const int wc = (wid & 1) << 6;
  const int fr = lane & 15;
  const int kq = lane >> 4;
  const int kqsw = kq ^ ((fr >> 1) & 3);

  const int srow = tid >> 2;
  const int skq  = (tid & 3) ^ ((tid >> 3) & 3);
  const f16* gA0 = A + (long)(brow + srow) * lda + skq * 8;
  const f16* gA1 = A + (long)(brow + 64 + srow) * lda + skq * 8;
  const f16* gB0 = B + (long)(bcol + srow) * ldb + skq * 8;
  const f16* gB1 = B + (long)(bcol + 64 + srow) * ldb + skq * 8;
  f16* lAd0 = &lA[tid * 8];
  f16* lAd1 = &lA[2048 + tid * 8];
  f16* lBd0 = &lB[tid * 8];
  f16* lBd1 = &lB[2048 + tid * 8];

  f32x4 acc[4][4] = {};

  for (int t = 0; t < K; t += 32) {
    gload16(gA0 + t, lAd0);
    gload16(gA1 + t, lAd1);
    gload16(gB0 + t, lBd0);
    gload16(gB1 + t, lBd1);
    __syncthreads();
    f16x8 av[4], bv[4];
#pragma unroll
    for (int m = 0; m < 4; m++)
      av[m] = *(const f16x8*)&lA[(wr + m * 16 + fr) * 32 + kqsw * 8];
#pragma unroll
    for (int n = 0; n < 4; n++)
      bv[n] = *(const f16x8*)&lB[(wc + n * 16 + fr) * 32 + kqsw * 8];
#pragma unroll
    for (int m = 0; m < 4; m++)
#pragma unroll
      for (int n = 0; n < 4; n++)
        acc[m][n] = __builtin_amdgcn_mfma_f32_16x16x32_f16(av[m], bv[n], acc[m][n], 0, 0, 0);
    __syncthreads();
  }

#pragma unroll
  for (int m = 0; m < 4; m++)
#pragma unroll
    for (int n = 0; n < 4; n++) {
      const int row0 = brow + wr + m * 16 + kq * 4;
      const int col  = bcol + wc + n * 16 + fr;
      if constexpr (TRANSC) {
        f16x4 v;
#pragma unroll
        for (int i = 0; i < 4; i++) v[i] = (f16)(acc[m][n][i] * alpha);
        *(f16x4*)&C[(long)col * ldc + row0] = v;
      } else {
        float bb = 0.f;
        if constexpr (BIAS) bb = bias[col];
#pragma unroll
        for (int i = 0; i < 4; i++)
          C[(long)(row0 + i) * ldc + col] = (OutT)(acc[m][n][i] * alpha + bb);
      }
    }
}

template<typename OutT, bool BIAS, bool TRANSC>
__global__ __launch_bounds__(256)
void gemm_bt(const f16* __restrict__ A, const f16* __restrict__ B,
             OutT* __restrict__ C, const float* __restrict__ bias,
             int K, int lda, int ldb, int ldc,
             long sA, long sB, long sC, float alpha)
{
  __shared__ f16 lA[128*32];
  __shared__ f16 lB[128*32];
  const int bz = blockIdx.z;
  gemm_body<OutT, BIAS, TRANSC>(A + bz * sA, B + bz * sB, C + bz * sC, bias,
                                K, lda, ldb, ldc, alpha, lA, lB);
}

// ---------------- f32 -> f16 convert (vectorized x4)
__global__ __launch_bounds__(256)
void cvt_f32_f16(const float* __restrict__ in, f16* __restrict__ out, long n4) {
  long i = (long)blockIdx.x * 256 + threadIdx.x;
  if (i >= n4) return;
  float4 v = ((const float4*)in)[i];
  f16x4 o = {(f16)v.x, (f16)v.y, (f16)v.z, (f16)v.w};
  ((f16x4*)out)[i] = o;
}

// ---------------- fused x: f32 -> (xh f16, xT f16 transposed) in one pass
__global__ __launch_bounds__(256)
void cvtT_x(const float* __restrict__ x, f16* __restrict__ xh, f16* __restrict__ xT) {
  __shared__ f16 t[32][33];
  const int b = blockIdx.z;
  const int s0 = blockIdx.x * 32, d0 = blockIdx.y * 32;
  const int tx = threadIdx.x, ty = threadIdx.y;  // (32,8)
#pragma unroll
  for (int j = 0; j < 32; j += 8) {
    const long idx = ((long)b * 2048 + s0 + ty + j) * 1024 + d0 + tx;
    f16 h = (f16)x[idx];
    xh[idx] = h;
    t[ty + j][tx] = h;
  }
  __syncthreads();
#pragma unroll
  for (int j = 0; j < 32; j += 8)
    xT[((long)b * 1024 + d0 + ty + j) * 2048 + s0 + tx] = t[tx][ty + j];
}

// ---------------- fused masked transposes of q,k and plain transpose of v
// z = tau*4 + b; tau: 0 -> PqT (masked), 1 -> PkT (masked), 2 -> vT (plain)
__global__ __launch_bounds__(256)
void qkvT(const f16* __restrict__ qkv, const float* __restrict__ nq,
          const float* __restrict__ nk, const float* __restrict__ thr,
          f16* __restrict__ PqT, f16* __restrict__ PkT, f16* __restrict__ vT) {
  __shared__ f16 t[32][33];
  const int z = blockIdx.z, tau = z >> 2, b = z & 3;
  f16* dst = (tau == 0) ? PqT : (tau == 1) ? PkT : vT;
  const f16* src = qkv + (long)b * 2048 * 3072 + tau * 1024;
  const int s0 = blockIdx.x * 32, d0 = blockIdx.y * 32;
  const int tx = threadIdx.x, ty = threadIdx.y;  // (32,8)
  if (tau < 2) {
    const float* nrm = (tau ? nk : nq) + (long)b * 1024 * 512;
    const float tb = thr[tau * 4 + b];
#pragma unroll
    for (int j = 0; j < 32; j += 8) {
      const int s = s0 + ty + j, d = d0 + tx;
      f16 v = src[(long)s * 3072 + d];
      t[ty + j][tx] = (nrm[(long)(s >> 1) * 512 + (d >> 1)] >= tb) ? v : (f16)0.f;
    }
  } else {
#pragma unroll
    for (int j = 0; j < 32; j += 8)
      t[ty + j][tx] = src[(long)(s0 + ty + j) * 3072 + d0 + tx];
  }
  __syncthreads();
#pragma unroll
  for (int j = 0; j < 32; j += 8)
    dst[((long)b * 1024 + d0 + ty + j) * 2048 + s0 + tx] = t[tx][ty + j];
}

// ---------------- 2x2 tile norms^2 for q (tau=0) and k (tau=1) slices of qkv
__global__ __launch_bounds__(256)
void tile_norms(const f16* __restrict__ qkv, float* __restrict__ nq, float* __restrict__ nk) {
  long i = (long)blockIdx.x * 256 + threadIdx.x;  // 4*1024*128 per tensor
  const int tau = blockIdx.y;
  const int d8 = (int)(i & 127);
  const int s2 = (int)((i >> 7) & 1023);
  const int b  = (int)(i >> 17);
  const f16* p0 = qkv + ((long)b * 2048 + 2 * s2) * 3072 + tau * 1024 + d8 * 8;
  f16x8 r0 = *(const f16x8*)p0;
  f16x8 r1 = *(const f16x8*)(p0 + 3072);
  float oo[4];
#pragma unroll
  for (int j = 0; j < 4; j++) {
    float a = (float)r0[2*j], c = (float)r0[2*j+1];
    float d = (float)r1[2*j], e = (float)r1[2*j+1];
    oo[j] = a*a + c*c + d*d + e*e;
  }
  float* dst = (tau ? nk : nq) + ((long)b * 1024 + s2) * 512 + d8 * 4;
  float4 o = {oo[0], oo[1], oo[2], oo[3]};
  *(float4*)dst = o;
}

// ---------------- WO row norms^2 (exact f32): one wave per row of (8192,1024)
__global__ __launch_bounds__(256)
void row_norms(const float* __restrict__ WO, float* __restrict__ wno) {
  const int wid = threadIdx.x >> 6, lane = threadIdx.x & 63;
  const long row = (long)blockIdx.x * 4 + wid;
  const float* p = WO + row * 1024;
  float s = 0.f;
#pragma unroll
  for (int j = 0; j < 4; j++) {
    float4 v = *(const float4*)(p + lane * 4 + j * 256);
    s += v.x*v.x + v.y*v.y + v.z*v.z + v.w*v.w;
  }
  for (int off = 32; off; off >>= 1) s += __shfl_down(s, off, 64);
  if (lane == 0) wno[row] = s;
}

// ---------------- exact radix-select of rank-r value (upper-middle order stat)
__global__ __launch_bounds__(256)
void select_init(unsigned* hist, unsigned* prefix, unsigned* rankrem) {
  int i = blockIdx.x * 256 + threadIdx.x;
  if (i < 12 * 2048) hist[i] = 0;
  if (i < 12) { prefix[i] = 0; rankrem[i] = (i < 8) ? 262144u : 1024u; }
}

__global__ __launch_bounds__(256)
void hist_pass(const float* __restrict__ nq, const float* __restrict__ nk,
               const float* __restrict__ wno, unsigned* __restrict__ hist,
               const unsigned* __restrict__ prefix,
               int shift, int nbins, unsigned himask) {
  __shared__ unsigned lh[2048];
  const int pid = blockIdx.y;
  for (int i = threadIdx.x; i < nbins; i += 256) lh[i] = 0;
  __syncthreads();
  const float* base; long N;
  if (pid < 4)      { base = nq  + (long)pid       * 524288; N = 524288; }
  else if (pid < 8) { base = nk  + (long)(pid - 4) * 524288; N = 524288; }
  else              { base = wno + (long)(pid - 8) * 2048;   N = 2048;  }
  const unsigned pref = prefix[pid];
  long chunk = (N + gridDim.x - 1) / gridDim.x;
  long s = (long)blockIdx.x * chunk;
  long e = s + chunk; if (e > N) e = N;
  for (long i = s + threadIdx.x; i < e; i += 256) {
    unsigned u = __float_as_uint(base[i]);
    if ((u & himask) == pref) atomicAdd(&lh[(u >> shift) & (nbins - 1)], 1u);
  }
  __syncthreads();
  for (int i = threadIdx.x; i < nbins; i += 256)
    if (lh[i]) atomicAdd(&hist[pid * 2048 + i], lh[i]);
}

// Parallel scan: 256 threads each own nbins/256 bins; Hillis-Steele over chunk sums.
__global__ __launch_bounds__(256)
void scan_pass(unsigned* __restrict__ hist, unsigned* __restrict__ prefix,
               unsigned* __restrict__ rankrem, float* __restrict__ thr,
               int shift, int nbins, int final_pass) {
  __shared__ unsigned buf[2][256];
  const int pid = blockIdx.x;
  const int tid = threadIdx.x;
  unsigned* h = hist + pid * 2048;
  const int per = nbins >> 8;  // 8 or 4
  const unsigned r = rankrem[pid];
  const unsigned oldpref = prefix[pid];
  unsigned local[8];
  unsigned s = 0;
#pragma unroll
  for (int j = 0; j < 8; j++) {
    if (j < per) {
      local[j] = h[tid * per + j];
      h[tid * per + j] = 0;
      s += local[j];
    }
  }
  buf[0][tid] = s;
  __syncthreads();
  int src = 0;
#pragma unroll
  for (int d = 1; d < 256; d <<= 1) {
    unsigned v = buf[src][tid];
    if (tid >= d) v += buf[src][tid - d];
    buf[src ^ 1][tid] = v;
    __syncthreads();
    src ^= 1;
  }
  const unsigned incl = buf[src][tid];
  const unsigned excl = incl - s;
  if (excl <= r && r < incl) {
    unsigned accu = excl;
#pragma unroll
    for (int j = 0; j < 8; j++) {
      if (j < per) {
        if (accu + local[j] > r) {
          rankrem[pid] = r - accu;
          unsigned np = oldpref | ((unsigned)(tid * per + j) << shift);
          prefix[pid] = np;
          if (final_pass) thr[pid] = __uint_as_float(np);
          break;
        }
        accu += local[j];
      }
    }
  }
}

// ---------------- fused WO row-mask + transpose + f32->f16: WO (b,2048,1024) -> WOT (b,1024,2048)
__global__ __launch_bounds__(256)
void wo_maskT(const float* __restrict__ WO, const float* __restrict__ wno,
              const float* __restrict__ thr, f16* __restrict__ WOT) {
  __shared__ f16 t[32][33];
  const int b = blockIdx.z;
  const int s0 = blockIdx.x * 32, d0 = blockIdx.y * 32;
  const int tx = threadIdx.x, ty = threadIdx.y;  // (32,8)
  const float tb = thr[8 + b];
#pragma unroll
  for (int j = 0; j < 32; j += 8) {
    const int s = s0 + ty + j;
    const float m = (wno[(long)b * 2048 + s] >= tb) ? 1.f : 0.f;
    t[ty + j][tx] = (f16)(WO[((long)b * 2048 + s) * 1024 + d0 + tx] * m);
  }
  __syncthreads();
#pragma unroll
  for (int j = 0; j < 32; j += 8)
    WOT[((long)b * 1024 + d0 + ty + j) * 2048 + s0 + tx] = t[tx][ty + j];
}

extern "C" void kernel_launch(void* const* d_in, const int* in_sizes, int n_in,
                              void* d_out, int out_size, void* d_ws, size_t ws_size,
                              hipStream_t stream) {
  const float* x    = (const float*)d_in[0];   // (4,2048,1024)
  const float* Wqkv = (const float*)d_in[1];   // (3072,1024)
  const float* bqkv = (const float*)d_in[2];   // (3072,)
  const float* WO   = (const float*)d_in[3];   // (4,1,2048,1024)
  float* out = (float*)d_out;                  // (4,2048,1024) f32

  char* w = (char*)d_ws;
  auto alloc = [&](size_t bytes) { char* p = w; w += (bytes + 255) & ~(size_t)255; return p; };
  f16*      xh      = (f16*)alloc(8192L * 1024 * 2);
  f16*      wh      = (f16*)alloc(3072L * 1024 * 2);
  f16*      xT      = (f16*)alloc(4L * 1024 * 2048 * 2);
  f16*      qkv     = (f16*)alloc(8192L * 3072 * 2);
  float*    nq      = (float*)alloc(4L * 524288 * 4);
  float*    nk      = (float*)alloc(4L * 524288 * 4);
  float*    wno     = (float*)alloc(8192L * 4);
  unsigned* hist    = (unsigned*)alloc(12L * 2048 * 4);
  unsigned* prefix  = (unsigned*)alloc(256);
  unsigned* rankrem = (unsigned*)alloc(256);
  float*    thr     = (float*)alloc(256);
  f16*      WOT     = (f16*)alloc(4L * 1024 * 2048 * 2);
  f16*      PqT     = (f16*)alloc(4L * 1024 * 2048 * 2);
  f16*      PkT     = (f16*)alloc(4L * 1024 * 2048 * 2);
  f16*      vT      = (f16*)alloc(4L * 1024 * 2048 * 2);
  f16*      Zt      = (f16*)alloc(4L * 1024 * 1024 * 2);
  f16*      A1      = (f16*)alloc(4L * 1024 * 1024 * 2);
  f16*      B2      = (f16*)alloc(4L * 1024 * 1024 * 2);
  f16*      M1      = (f16*)alloc(4L * 1024 * 1024 * 2);
  f16*      M2T     = (f16*)alloc(4L * 1024 * 1024 * 2);
  if ((size_t)(w - (char*)d_ws) > ws_size) return;  // workspace too small: fail visibly

  // 1. conversions: x -> (xh, xT) fused; Wqkv -> wh
  cvtT_x<<<dim3(64, 32, 4), dim3(32, 8), 0, stream>>>(x, xh, xT);
  cvt_f32_f16<<<3072, 256, 0, stream>>>(Wqkv, wh, 3072L * 1024 / 4);
  // 2. qkv = x @ Wqkv^T + bqkv  (M=8192,N=3072,K=1024), 256^2 reg-dbuf pipelined GEMM
  gemm256_qkv<<<dim3(12, 32, 1), 512, 0, stream>>>(xh, wh, qkv, bqkv);
  // 3. norms
  tile_norms<<<dim3(2048, 2), 256, 0, stream>>>(qkv, nq, nk);
  row_norms<<<2048, 256, 0, stream>>>(WO, wno);
  // 4. exact medians via 3-pass radix select (bits 31:21 / 20:10 / 9:0)
  select_init<<<96, 256, 0, stream>>>(hist, prefix, rankrem);
  hist_pass<<<dim3(32, 12), 256, 0, stream>>>(nq, nk, wno, hist, prefix, 21, 2048, 0u);
  scan_pass<<<12, 256, 0, stream>>>(hist, prefix, rankrem, thr, 21, 2048, 0);
  hist_pass<<<dim3(32, 12), 256, 0, stream>>>(nq, nk, wno, hist, prefix, 10, 2048, 0xFFE00000u);
  scan_pass<<<12, 256, 0, stream>>>(hist, prefix, rankrem, thr, 10, 2048, 0);
  hist_pass<<<dim3(32, 12), 256, 0, stream>>>(nq, nk, wno, hist, prefix, 0, 1024, 0xFFFFFC00u);
  scan_pass<<<12, 256, 0, stream>>>(hist, prefix, rankrem, thr, 0, 1024, 1);
  // 5. masked transposes (mask fused into transpose read) + WO mask-transpose
  qkvT<<<dim3(64, 32, 12), dim3(32, 8), 0, stream>>>(qkv, nq, nk, thr, PqT, PkT, vT);
  wo_maskT<<<dim3(64, 32, 4), dim3(32, 8), 0, stream>>>(WO, wno, thr, WOT);
  // 6. reassociated chain: out = x·[Pq^T·Pk]·[x^T·v]·[WO_^T·x]/32
  // stage 1 (merged, 192 blocks, 256^2 pipelined): A1 = Pq^T·Pk/32 ; B2 = v^T·x/32 ; Zt = x^T·WO_/32
  gemm3_256<<<dim3(4, 4, 12), 512, 0, stream>>>(
      PqT, PkT, A1, vT, xT, B2, xT, WOT, Zt, 0.03125f);
  // stage 2: M1 = A1·B2^T
  gemm_bt<f16, false, false><<<dim3(8, 8, 4), 256, 0, stream>>>(
      A1, B2, M1, nullptr, 1024, 1024, 1024, 1024,
      1024L * 1024, 1024L * 1024, 1024L * 1024, 1.f);
  // stage 3: M2T = (M1·Zt^T)^T / 4
  gemm_bt<f16, false, true><<<dim3(8, 8, 4), 256, 0, stream>>>(
      M1, Zt, M2T, nullptr, 1024, 1024, 1024, 1024,
      1024L * 1024, 1024L * 1024, 1024L * 1024, 0.25f);
  // stage 4: out = x·M2 · 4096  (total scale 4096/2^17 = 1/32)
  gemm_bt<float, false, false><<<dim3(8, 16, 4), 256, 0, stream>>>(
      xh, M2T, out, nullptr, 1024, 1024, 1024, 1024,
      2048L * 1024, 1024L * 1024, 2048L * 1024, 4096.f);
}

// Round 6
// 330.497 us; speedup vs baseline: 2.0989x; 1.0771x over previous
//
#include <hip/hip_runtime.h>

typedef _Float16 f16;
typedef _Float16 f16x8 __attribute__((ext_vector_type(8)));
typedef _Float16 f16x4 __attribute__((ext_vector_type(4)));
typedef float f32x4 __attribute__((ext_vector_type(4)));

__device__ __forceinline__ void gload16(const void* g, void* l) {
  __builtin_amdgcn_global_load_lds(
      (const __attribute__((address_space(1))) void*)g,
      (__attribute__((address_space(3))) void*)l, 16, 0, 0);
}

#define SCHED_FENCE __builtin_amdgcn_sched_barrier(0)
#define RAW_BARRIER do { SCHED_FENCE; __builtin_amdgcn_s_barrier(); SCHED_FENCE; } while (0)
#define WAIT_VM_0    do { asm volatile("s_waitcnt vmcnt(0)"     ::: "memory"); SCHED_FENCE; } while (0)
#define WAIT_VM_4    do { asm volatile("s_waitcnt vmcnt(4)"     ::: "memory"); SCHED_FENCE; } while (0)
#define WAIT_VM_8    do { asm volatile("s_waitcnt vmcnt(8)"     ::: "memory"); SCHED_FENCE; } while (0)
#define WAIT_LGKM_0  do { asm volatile("s_waitcnt lgkmcnt(0)"   ::: "memory"); SCHED_FENCE; } while (0)
#define WAIT_LGKM_12 do { asm volatile("s_waitcnt lgkmcnt(12)"  ::: "memory"); SCHED_FENCE; } while (0)

// ================= 256x256-tile GEMM, BK=32, 4-deep LDS pipeline (R5-verified) ==========
// brow/bcol passed in (callers apply XCD swizzle).
template<bool BIAS>
__device__ __forceinline__ void gemm256_body(
    const f16* __restrict__ A, const f16* __restrict__ B, f16* __restrict__ C,
    const float* __restrict__ bias, int K, int lda, int ldb, int ldc, float alpha,
    f16* lds, int brow, int bcol)
{
  const int NT = K >> 5;
  const int tid = threadIdx.x;
  const int lane = tid & 63;
  const int wid = tid >> 6;
  const int wr = wid >> 2;
  const int wc = wid & 3;
  const int fr = lane & 15;
  const int kq = lane >> 4;

  const f16* pA[2]; const f16* pB[2]; int pdst[2];
#pragma unroll
  for (int i = 0; i < 2; i++) {
    const int p = wid * 128 + i * 64 + lane;
    const int rr = ((p >> 6) << 4) | ((p >> 2) & 15);
    const int c4 = (p & 3) ^ ((p >> 3) & 3);
    pA[i] = A + (long)(brow + rr) * lda + c4 * 8;
    pB[i] = B + (long)(bcol + rr) * ldb + c4 * 8;
    pdst[i] = p * 8;
  }

  auto STAGE = [&](int t) {
    f16* base = lds + (t & 3) * 16384;
    const int off = t * 32;
#pragma unroll
    for (int i = 0; i < 2; i++) {
      gload16(pA[i] + off, base + pdst[i]);
      gload16(pB[i] + off, base + 8192 + pdst[i]);
    }
  };

  const int aoff0 = fr * 4 + (kq ^ ((fr >> 1) & 3));
  f32x4 acc[8][4] = {};
  f16x8 avA[8], bvA[4], avB[8], bvB[4];

  STAGE(0); STAGE(1); STAGE(2);
  WAIT_VM_4;
  RAW_BARRIER;
#pragma unroll
  for (int m = 0; m < 8; m++)
    avA[m] = *(const f16x8*)(lds + ((wr * 8 + m) * 64 + aoff0) * 8);
#pragma unroll
  for (int n = 0; n < 4; n++)
    bvA[n] = *(const f16x8*)(lds + 8192 + ((wc * 4 + n) * 64 + aoff0) * 8);

#define GEMM_ITER(T, AVC, BVC, AVN, BVN)                                        \
  do {                                                                          \
    if ((T) + 3 < NT) STAGE((T) + 3);                                           \
    if ((T) + 1 < NT) {                                                         \
      const f16* nb_ = lds + (((T) + 1) & 3) * 16384;                           \
      _Pragma("unroll")                                                         \
      for (int m = 0; m < 8; m++)                                               \
        AVN[m] = *(const f16x8*)(nb_ + ((wr * 8 + m) * 64 + aoff0) * 8);        \
      _Pragma("unroll")                                                         \
      for (int n = 0; n < 4; n++)                                               \
        BVN[n] = *(const f16x8*)(nb_ + 8192 + ((wc * 4 + n) * 64 + aoff0) * 8); \
      WAIT_LGKM_12;                                                             \
    } else {                                                                    \
      WAIT_LGKM_0;                                                              \
    }                                                                           \
    __builtin_amdgcn_s_setprio(1);                                              \
    _Pragma("unroll")                                                           \
    for (int m = 0; m < 8; m++)                                                 \
      _Pragma("unroll")                                                         \
      for (int n = 0; n < 4; n++)                                               \
        acc[m][n] = __builtin_amdgcn_mfma_f32_16x16x32_f16(AVC[m], BVC[n],      \
                                                           acc[m][n], 0, 0, 0); \
    __builtin_amdgcn_s_setprio(0);                                              \
    if ((T) + 3 < NT)      { WAIT_VM_4; }                                       \
    else if ((T) + 2 < NT) { WAIT_VM_0; }                                       \
    RAW_BARRIER;                                                                \
  } while (0)

#pragma unroll 1
  for (int t = 0; t < NT; t += 2) {
    GEMM_ITER(t,     avA, bvA, avB, bvB);
    GEMM_ITER(t + 1, avB, bvB, avA, bvA);
  }
#undef GEMM_ITER

#pragma unroll
  for (int m = 0; m < 8; m++) {
    const int row0 = brow + wr * 128 + m * 16 + kq * 4;
#pragma unroll
    for (int n = 0; n < 4; n++) {
      const int col = bcol + wc * 64 + n * 16 + fr;
      float bb = 0.f;
      if constexpr (BIAS) bb = bias[col];
#pragma unroll
      for (int i = 0; i < 4; i++)
        C[(long)(row0 + i) * ldc + col] = (f16)(acc[m][n][i] * alpha + bb);
    }
  }
}

// qkv: grid (12,32); XCD-chunked swizzle (nwg=384, 384%8==0): slot s -> tile (s%8)*48+s/8
__global__ __launch_bounds__(512, 2)
void gemm256_qkv(const f16* __restrict__ A, const f16* __restrict__ B, f16* __restrict__ C,
                 const float* __restrict__ bias) {
  __shared__ f16 lds[65536];
  const int s = blockIdx.y * 12 + blockIdx.x;
  const int tile = (s & 7) * 48 + (s >> 3);
  gemm256_body<true>(A, B, C, bias, 1024, 1024, 1024, 3072, 1.f, lds,
                     (tile / 12) << 8, (tile % 12) << 8);
}

// merged stage-1: grid (4,4,12); swizzle nwg=192 (192%8==0): slot -> tile (s%8)*24+s/8
__global__ __launch_bounds__(512, 2)
void gemm3_256(const f16* __restrict__ Aa, const f16* __restrict__ Ba, f16* __restrict__ Ca,
               const f16* __restrict__ Ab, const f16* __restrict__ Bb, f16* __restrict__ Cb,
               const f16* __restrict__ Ac, const f16* __restrict__ Bc, f16* __restrict__ Cc,
               float alpha) {
  __shared__ f16 lds[65536];
  const int s = (blockIdx.z * 4 + blockIdx.y) * 4 + blockIdx.x;
  const int tile = (s & 7) * 24 + (s >> 3);
  const int z = tile >> 4, rem = tile & 15;
  const int p = z >> 2, b = z & 3;
  const f16* A; const f16* B; f16* C;
  if (p == 0)      { A = Aa; B = Ba; C = Ca; }
  else if (p == 1) { A = Ab; B = Bb; C = Cb; }
  else             { A = Ac; B = Bc; C = Cc; }
  A += (long)b * (1024L * 2048);
  B += (long)b * (1024L * 2048);
  C += (long)b * (1024L * 1024);
  gemm256_body<false>(A, B, C, nullptr, 2048, 2048, 2048, 1024, alpha, lds,
                      (rem >> 2) << 8, (rem & 3) << 8);
}

// ================= 128x128 GEMM, NEW: 4-buffer stage-lead-3 pipeline, counted vmcnt ========
// Targets the small chain stages (grids 256-512 blocks at 1-2 blocks/CU) where the old
// vmcnt(0)-drain-per-tile exposed full HBM latency. Per iter t: STAGE(t+3) -> reads+MFMA(t)
// -> lgkm0 -> vmcnt(8) [t+1 landed, t+2/t+3 in flight; never 0 mid-loop] -> raw barrier.
// Race ledger: STAGE(t+3) targets buf[(t-1)&3], readers done by barrier(t-1); per-wave vm
// gate + barrier certifies all waves' cooperative stage loads landed before any read.
template<typename OutT, bool BIAS, bool TRANSC>
__device__ __forceinline__ void gemm_body(
    const f16* __restrict__ A, const f16* __restrict__ B,
    OutT* __restrict__ C, const float* __restrict__ bias,
    int K, int lda, int ldb, int ldc, float alpha, f16* lds)
{
  const int NT = K >> 5;
  const int brow = blockIdx.y << 7;
  const int bcol = blockIdx.x << 7;
  const int tid = threadIdx.x;
  const int lane = tid & 63;
  const int wid = tid >> 6;
  const int wr = (wid >> 1) << 6;
  const int wc = (wid & 1) << 6;
  const int fr = lane & 15;
  const int kq = lane >> 4;
  const int kqsw = kq ^ ((fr >> 1) & 3);

  const int srow = tid >> 2;
  const int skq  = (tid & 3) ^ ((tid >> 3) & 3);
  const f16* gA0 = A + (long)(brow + srow) * lda + skq * 8;
  const f16* gA1 = A + (long)(brow + 64 + srow) * lda + skq * 8;
  const f16* gB0 = B + (long)(bcol + srow) * ldb + skq * 8;
  const f16* gB1 = B + (long)(bcol + 64 + srow) * ldb + skq * 8;
  const int dA0 = tid * 8, dA1 = 2048 + tid * 8;
  const int dB0 = 4096 + tid * 8, dB1 = 6144 + tid * 8;

  auto STAGE = [&](int t) {
    f16* base = lds + (t & 3) * 8192;   // 16KB (8192 f16) per buffer, 4 buffers = 64KB
    const int off = t * 32;
    gload16(gA0 + off, base + dA0);
    gload16(gA1 + off, base + dA1);
    gload16(gB0 + off, base + dB0);
    gload16(gB1 + off, base + dB1);
  };

  f32x4 acc[4][4] = {};

  STAGE(0); STAGE(1); STAGE(2);
  WAIT_VM_8;      // my stage-0 loads landed
  RAW_BARRIER;    // -> all waves' stage-0 landed

#pragma unroll 1
  for (int t = 0; t < NT; ++t) {
    if (t + 3 < NT) STAGE(t + 3);
    SCHED_FENCE;
    const f16* base = lds + (t & 3) * 8192;
    f16x8 av[4], bv[4];
#pragma unroll
    for (int m = 0; m < 4; m++)
      av[m] = *(const f16x8*)(base + (wr + m * 16 + fr) * 32 + kqsw * 8);
#pragma unroll
    for (int n = 0; n < 4; n++)
      bv[n] = *(const f16x8*)(base + 4096 + (wc + n * 16 + fr) * 32 + kqsw * 8);
    __builtin_amdgcn_s_setprio(1);
#pragma unroll
    for (int m = 0; m < 4; m++)
#pragma unroll
      for (int n = 0; n < 4; n++)
        acc[m][n] = __builtin_amdgcn_mfma_f32_16x16x32_f16(av[m], bv[n], acc[m][n], 0, 0, 0);
    __builtin_amdgcn_s_setprio(0);
    if (t + 1 < NT) {
      WAIT_LGKM_0;                           // my reads of tile t retired
      if (t + 3 < NT)      { WAIT_VM_8; }    // t+1 landed; t+2,t+3 in flight
      else if (t + 2 < NT) { WAIT_VM_4; }    // drain
      else                 { WAIT_VM_0; }
      RAW_BARRIER;
    }
  }

#pragma unroll
  for (int m = 0; m < 4; m++)
#pragma unroll
    for (int n = 0; n < 4; n++) {
      const int row0 = brow + wr + m * 16 + kq * 4;
      const int col  = bcol + wc + n * 16 + fr;
      if constexpr (TRANSC) {
        f16x4 v;
#pragma unroll
        for (int i = 0; i < 4; i++) v[i] = (f16)(acc[m][n][i] * alpha);
        *(f16x4*)&C[(long)col * ldc + row0] = v;
      } else {
        float bb = 0.f;
        if constexpr (BIAS) bb = bias[col];
#pragma unroll
        for (int i = 0; i < 4; i++)
          C[(long)(row0 + i) * ldc + col] = (OutT)(acc[m][n][i] * alpha + bb);
      }
    }
}

template<typename OutT, bool BIAS, bool TRANSC>
__global__ __launch_bounds__(256)
void gemm_bt(const f16* __restrict__ A, const f16* __restrict__ B,
             OutT* __restrict__ C, const float* __restrict__ bias,
             int K, int lda, int ldb, int ldc,
             long sA, long sB, long sC, float alpha)
{
  __shared__ f16 lds[32768];
  const int bz = blockIdx.z;
  gemm_body<OutT, BIAS, TRANSC>(A + bz * sA, B + bz * sB, C + bz * sC, bias,
                                K, lda, ldb, ldc, alpha, lds);
}

// ---------------- f32 -> f16 convert (vectorized x4)
__global__ __launch_bounds__(256)
void cvt_f32_f16(const float* __restrict__ in, f16* __restrict__ out, long n4) {
  long i = (long)blockIdx.x * 256 + threadIdx.x;
  if (i >= n4) return;
  float4 v = ((const float4*)in)[i];
  f16x4 o = {(f16)v.x, (f16)v.y, (f16)v.z, (f16)v.w};
  ((f16x4*)out)[i] = o;
}

// ---------------- fused x: f32 -> (xh f16, xT f16 transposed) in one pass
__global__ __launch_bounds__(256)
void cvtT_x(const float* __restrict__ x, f16* __restrict__ xh, f16* __restrict__ xT) {
  __shared__ f16 t[32][33];
  const int b = blockIdx.z;
  const int s0 = blockIdx.x * 32, d0 = blockIdx.y * 32;
  const int tx = threadIdx.x, ty = threadIdx.y;  // (32,8)
#pragma unroll
  for (int j = 0; j < 32; j += 8) {
    const long idx = ((long)b * 2048 + s0 + ty + j) * 1024 + d0 + tx;
    f16 h = (f16)x[idx];
    xh[idx] = h;
    t[ty + j][tx] = h;
  }
  __syncthreads();
#pragma unroll
  for (int j = 0; j < 32; j += 8)
    xT[((long)b * 1024 + d0 + ty + j) * 2048 + s0 + tx] = t[tx][ty + j];
}

// ---------------- fused norms: y<2 -> 2x2 tile norms^2 of q/k; y==2 -> WO row norms^2
__global__ __launch_bounds__(256)
void norms_all(const f16* __restrict__ qkv, const float* __restrict__ WO,
               float* __restrict__ nq, float* __restrict__ nk, float* __restrict__ wno) {
  if (blockIdx.y < 2) {
    long i = (long)blockIdx.x * 256 + threadIdx.x;
    const int tau = blockIdx.y;
    const int d8 = (int)(i & 127);
    const int s2 = (int)((i >> 7) & 1023);
    const int b  = (int)(i >> 17);
    const f16* p0 = qkv + ((long)b * 2048 + 2 * s2) * 3072 + tau * 1024 + d8 * 8;
    f16x8 r0 = *(const f16x8*)p0;
    f16x8 r1 = *(const f16x8*)(p0 + 3072);
    float oo[4];
#pragma unroll
    for (int j = 0; j < 4; j++) {
      float a = (float)r0[2*j], c = (float)r0[2*j+1];
      float d = (float)r1[2*j], e = (float)r1[2*j+1];
      oo[j] = a*a + c*c + d*d + e*e;
    }
    float* dst = (tau ? nk : nq) + ((long)b * 1024 + s2) * 512 + d8 * 4;
    float4 o = {oo[0], oo[1], oo[2], oo[3]};
    *(float4*)dst = o;
  } else {
    const int wid = threadIdx.x >> 6, lane = threadIdx.x & 63;
    const long row = (long)blockIdx.x * 4 + wid;
    const float* p = WO + row * 1024;
    float s = 0.f;
#pragma unroll
    for (int j = 0; j < 4; j++) {
      float4 v = *(const float4*)(p + lane * 4 + j * 256);
      s += v.x*v.x + v.y*v.y + v.z*v.z + v.w*v.w;
    }
    for (int off = 32; off; off >>= 1) s += __shfl_down(s, off, 64);
    if (lane == 0) wno[row] = s;
  }
}

// ---------------- exact radix-select of rank-r value (upper-middle order stat)
__global__ __launch_bounds__(256)
void select_init(unsigned* hist, unsigned* prefix, unsigned* rankrem) {
  int i = blockIdx.x * 256 + threadIdx.x;
  if (i < 12 * 2048) hist[i] = 0;
  if (i < 12) { prefix[i] = 0; rankrem[i] = (i < 8) ? 262144u : 1024u; }
}

__global__ __launch_bounds__(256)
void hist_pass(const float* __restrict__ nq, const float* __restrict__ nk,
               const float* __restrict__ wno, unsigned* __restrict__ hist,
               const unsigned* __restrict__ prefix,
               int shift, int nbins, unsigned himask) {
  __shared__ unsigned lh[2048];
  const int pid = blockIdx.y;
  for (int i = threadIdx.x; i < nbins; i += 256) lh[i] = 0;
  __syncthreads();
  const float* base; long N;
  if (pid < 4)      { base = nq  + (long)pid       * 524288; N = 524288; }
  else if (pid < 8) { base = nk  + (long)(pid - 4) * 524288; N = 524288; }
  else              { base = wno + (long)(pid - 8) * 2048;   N = 2048;  }
  const unsigned pref = prefix[pid];
  long chunk = (N + gridDim.x - 1) / gridDim.x;
  long s = (long)blockIdx.x * chunk;
  long e = s + chunk; if (e > N) e = N;
  for (long i = s + threadIdx.x; i < e; i += 256) {
    unsigned u = __float_as_uint(base[i]);
    if ((u & himask) == pref) atomicAdd(&lh[(u >> shift) & (nbins - 1)], 1u);
  }
  __syncthreads();
  for (int i = threadIdx.x; i < nbins; i += 256)
    if (lh[i]) atomicAdd(&hist[pid * 2048 + i], lh[i]);
}

// Parallel scan: 256 threads each own nbins/256 bins; Hillis-Steele over chunk sums.
__global__ __launch_bounds__(256)
void scan_pass(unsigned* __restrict__ hist, unsigned* __restrict__ prefix,
               unsigned* __restrict__ rankrem, float* __restrict__ thr,
               int shift, int nbins, int final_pass) {
  __shared__ unsigned buf[2][256];
  const int pid = blockIdx.x;
  const int tid = threadIdx.x;
  unsigned* h = hist + pid * 2048;
  const int per = nbins >> 8;  // 8 or 4
  const unsigned r = rankrem[pid];
  const unsigned oldpref = prefix[pid];
  unsigned local[8];
  unsigned s = 0;
#pragma unroll
  for (int j = 0; j < 8; j++) {
    if (j < per) {
      local[j] = h[tid * per + j];
      h[tid * per + j] = 0;
      s += local[j];
    }
  }
  buf[0][tid] = s;
  __syncthreads();
  int src = 0;
#pragma unroll
  for (int d = 1; d < 256; d <<= 1) {
    unsigned v = buf[src][tid];
    if (tid >= d) v += buf[src][tid - d];
    buf[src ^ 1][tid] = v;
    __syncthreads();
    src ^= 1;
  }
  const unsigned incl = buf[src][tid];
  const unsigned excl = incl - s;
  if (excl <= r && r < incl) {
    unsigned accu = excl;
#pragma unroll
    for (int j = 0; j < 8; j++) {
      if (j < per) {
        if (accu + local[j] > r) {
          rankrem[pid] = r - accu;
          unsigned np = oldpref | ((unsigned)(tid * per + j) << shift);
          prefix[pid] = np;
          if (final_pass) thr[pid] = __uint_as_float(np);
          break;
        }
        accu += local[j];
      }
    }
  }
}

// ---------------- fused transposes: z<12 -> masked q/k + plain v; z>=12 -> WO mask-transpose
__global__ __launch_bounds__(256)
void transAll(const f16* __restrict__ qkv, const float* __restrict__ nq,
              const float* __restrict__ nk, const float* __restrict__ thr,
              const float* __restrict__ WO, const float* __restrict__ wno,
              f16* __restrict__ PqT, f16* __restrict__ PkT, f16* __restrict__ vT,
              f16* __restrict__ WOT) {
  __shared__ f16 t[32][33];
  const int z = blockIdx.z;
  const int s0 = blockIdx.x * 32, d0 = blockIdx.y * 32;
  const int tx = threadIdx.x, ty = threadIdx.y;  // (32,8)
  if (z < 12) {
    const int tau = z >> 2, b = z & 3;
    f16* dst = (tau == 0) ? PqT : (tau == 1) ? PkT : vT;
    const f16* src = qkv + (long)b * 2048 * 3072 + tau * 1024;
    if (tau < 2) {
      const float* nrm = (tau ? nk : nq) + (long)b * 1024 * 512;
      const float tb = thr[tau * 4 + b];
#pragma unroll
      for (int j = 0; j < 32; j += 8) {
        const int s = s0 + ty + j, d = d0 + tx;
        f16 v = src[(long)s * 3072 + d];
        t[ty + j][tx] = (nrm[(long)(s >> 1) * 512 + (d >> 1)] >= tb) ? v : (f16)0.f;
      }
    } else {
#pragma unroll
      for (int j = 0; j < 32; j += 8)
        t[ty + j][tx] = src[(long)(s0 + ty + j) * 3072 + d0 + tx];
    }
    __syncthreads();
#pragma unroll
    for (int j = 0; j < 32; j += 8)
      dst[((long)b * 1024 + d0 + ty + j) * 2048 + s0 + tx] = t[tx][ty + j];
  } else {
    const int b = z - 12;
    const float tb = thr[8 + b];
#pragma unroll
    for (int j = 0; j < 32; j += 8) {
      const int s = s0 + ty + j;
      const float m = (wno[(long)b * 2048 + s] >= tb) ? 1.f : 0.f;
      t[ty + j][tx] = (f16)(WO[((long)b * 2048 + s) * 1024 + d0 + tx] * m);
    }
    __syncthreads();
#pragma unroll
    for (int j = 0; j < 32; j += 8)
      WOT[((long)b * 1024 + d0 + ty + j) * 2048 + s0 + tx] = t[tx][ty + j];
  }
}

extern "C" void kernel_launch(void* const* d_in, const int* in_sizes, int n_in,
                              void* d_out, int out_size, void* d_ws, size_t ws_size,
                              hipStream_t stream) {
  const float* x    = (const float*)d_in[0];   // (4,2048,1024)
  const float* Wqkv = (const float*)d_in[1];   // (3072,1024)
  const float* bqkv = (const float*)d_in[2];   // (3072,)
  const float* WO   = (const float*)d_in[3];   // (4,1,2048,1024)
  float* out = (float*)d_out;                  // (4,2048,1024) f32

  char* w = (char*)d_ws;
  auto alloc = [&](size_t bytes) { char* p = w; w += (bytes + 255) & ~(size_t)255; return p; };
  f16*      xh      = (f16*)alloc(8192L * 1024 * 2);
  f16*      wh      = (f16*)alloc(3072L * 1024 * 2);
  f16*      xT      = (f16*)alloc(4L * 1024 * 2048 * 2);
  f16*      qkv     = (f16*)alloc(8192L * 3072 * 2);
  float*    nq      = (float*)alloc(4L * 524288 * 4);
  float*    nk      = (float*)alloc(4L * 524288 * 4);
  float*    wno     = (float*)alloc(8192L * 4);
  unsigned* hist    = (unsigned*)alloc(12L * 2048 * 4);
  unsigned* prefix  = (unsigned*)alloc(256);
  unsigned* rankrem = (unsigned*)alloc(256);
  float*    thr     = (float*)alloc(256);
  f16*      WOT     = (f16*)alloc(4L * 1024 * 2048 * 2);
  f16*      PqT     = (f16*)alloc(4L * 1024 * 2048 * 2);
  f16*      PkT     = (f16*)alloc(4L * 1024 * 2048 * 2);
  f16*      vT      = (f16*)alloc(4L * 1024 * 2048 * 2);
  f16*      Zt      = (f16*)alloc(4L * 1024 * 1024 * 2);
  f16*      A1      = (f16*)alloc(4L * 1024 * 1024 * 2);
  f16*      B2      = (f16*)alloc(4L * 1024 * 1024 * 2);
  f16*      M1      = (f16*)alloc(4L * 1024 * 1024 * 2);
  f16*      M2T     = (f16*)alloc(4L * 1024 * 1024 * 2);
  if ((size_t)(w - (char*)d_ws) > ws_size) return;  // workspace too small: fail visibly

  // 1. conversions: x -> (xh, xT) fused; Wqkv -> wh
  cvtT_x<<<dim3(64, 32, 4), dim3(32, 8), 0, stream>>>(x, xh, xT);
  cvt_f32_f16<<<3072, 256, 0, stream>>>(Wqkv, wh, 3072L * 1024 / 4);
  // 2. qkv = x @ Wqkv^T + bqkv  (M=8192,N=3072,K=1024), 256^2 pipelined + XCD swizzle
  gemm256_qkv<<<dim3(12, 32, 1), 512, 0, stream>>>(xh, wh, qkv, bqkv);
  // 3. norms (fused tile+row)
  norms_all<<<dim3(2048, 3), 256, 0, stream>>>(qkv, WO, nq, nk, wno);
  // 4. exact medians via 3-pass radix select (bits 31:21 / 20:10 / 9:0)
  select_init<<<96, 256, 0, stream>>>(hist, prefix, rankrem);
  hist_pass<<<dim3(32, 12), 256, 0, stream>>>(nq, nk, wno, hist, prefix, 21, 2048, 0u);
  scan_pass<<<12, 256, 0, stream>>>(hist, prefix, rankrem, thr, 21, 2048, 0);
  hist_pass<<<dim3(32, 12), 256, 0, stream>>>(nq, nk, wno, hist, prefix, 10, 2048, 0xFFE00000u);
  scan_pass<<<12, 256, 0, stream>>>(hist, prefix, rankrem, thr, 10, 2048, 0);
  hist_pass<<<dim3(32, 12), 256, 0, stream>>>(nq, nk, wno, hist, prefix, 0, 1024, 0xFFFFFC00u);
  scan_pass<<<12, 256, 0, stream>>>(hist, prefix, rankrem, thr, 0, 1024, 1);
  // 5. fused masked transposes + WO mask-transpose
  transAll<<<dim3(64, 32, 16), dim3(32, 8), 0, stream>>>(
      qkv, nq, nk, thr, WO, wno, PqT, PkT, vT, WOT);
  // 6. reassociated chain: out = x·[Pq^T·Pk]·[x^T·v]·[WO_^T·x]/32
  // stage 1 (merged, 192 blocks, swizzled): A1 = Pq^T·Pk/32 ; B2 = v^T·x/32 ; Zt = x^T·WO_/32
  gemm3_256<<<dim3(4, 4, 12), 512, 0, stream>>>(
      PqT, PkT, A1, vT, xT, B2, xT, WOT, Zt, 0.03125f);
  // stage 2: M1 = A1·B2^T   (new 4-buffer pipelined 128^2)
  gemm_bt<f16, false, false><<<dim3(8, 8, 4), 256, 0, stream>>>(
      A1, B2, M1, nullptr, 1024, 1024, 1024, 1024,
      1024L * 1024, 1024L * 1024, 1024L * 1024, 1.f);
  // stage 3: M2T = (M1·Zt^T)^T / 4
  gemm_bt<f16, false, true><<<dim3(8, 8, 4), 256, 0, stream>>>(
      M1, Zt, M2T, nullptr, 1024, 1024, 1024, 1024,
      1024L * 1024, 1024L * 1024, 1024L * 1024, 0.25f);
  // stage 4: out = x·M2 · 4096  (total scale 4096/2^17 = 1/32)
  gemm_bt<float, false, false><<<dim3(8, 16, 4), 256, 0, stream>>>(
      xh, M2T, out, nullptr, 1024, 1024, 1024, 1024,
      2048L * 1024, 1024L * 1024, 2048L * 1024, 4096.f);
}